// Round 2
// baseline (9341.826 us; speedup 1.0000x reference)
//
#include <hip/hip_runtime.h>
#include <hip/hip_bf16.h>

// ---------------- problem constants ----------------
#define BSZ 2
#define LSEQ 2048
#define DIM 1024
#define VOCAB 32000
#define NLAYER 4
#define DSTATE 128
#define DCONV 4
#define HEADDIM 64
#define DIN 2048
#define NH 32
#define CONVDIM 2304          // DIN + 2*DSTATE
#define DPROJ 4384            // 2*DIN + 2*DSTATE + NH
#define FFN 4096
#define QLEN 128
#define NTOK 4096             // BSZ*LSEQ
#define NCHUNK 32             // NTOK/QLEN
#define CPB 16                // chunks per batch

using f32x4 = __attribute__((ext_vector_type(4))) float;
using s16x4 = __attribute__((ext_vector_type(4))) short;
using s16x8 = __attribute__((ext_vector_type(8))) short;

__device__ __forceinline__ short f2b(float f) {
  unsigned u = __builtin_bit_cast(unsigned, f);
  u += 0x7FFFu + ((u >> 16) & 1u);
  return (short)(u >> 16);
}
__device__ __forceinline__ float b2f(short s) {
  unsigned u = ((unsigned)(unsigned short)s) << 16;
  return __builtin_bit_cast(float, u);
}
__device__ __forceinline__ void gld16(const short* g, short* l) {
  __builtin_amdgcn_global_load_lds(
      (const __attribute__((address_space(1))) unsigned int*)g,
      (__attribute__((address_space(3))) unsigned int*)l, 16, 0, 0);
}

// ---------------- single-bf16 GEMM (lm-head): C = A * B^T + bias ----------------
__global__ __launch_bounds__(256) void gemm_bt(
    const short* __restrict__ A, const short* __restrict__ B,
    float* __restrict__ Cf, const float* __restrict__ bias,
    int N, int K, int ldc)
{
  __shared__ short lA[4096];
  __shared__ short lB[4096];
  const int tid  = threadIdx.x;
  const int lane = tid & 63;
  const int wid  = tid >> 6;
  const int m0 = blockIdx.y * 128;
  const int n0 = blockIdx.x * 128;

  const int r0 = tid >> 2;
  const int kc = (tid & 3) << 3;
  const short* ga0 = A + (size_t)(m0 + r0) * K + kc;
  const short* ga1 = ga0 + (size_t)64 * K;
  int nr0 = n0 + r0;      if (nr0 > N - 1) nr0 = N - 1;
  int nr1 = n0 + 64 + r0; if (nr1 > N - 1) nr1 = N - 1;
  const short* gb0 = B + (size_t)nr0 * K + kc;
  const short* gb1 = B + (size_t)nr1 * K + kc;

  const int fr = lane & 15;
  const int fk = (lane >> 4) << 3;
  const int wm = (wid >> 1) << 6;
  const int wn = (wid & 1) << 6;

  f32x4 acc[4][4] = {};

  for (int kk = 0; kk < K; kk += 32) {
    gld16(ga0 + kk, &lA[tid * 8]);
    gld16(ga1 + kk, &lA[2048 + tid * 8]);
    gld16(gb0 + kk, &lB[tid * 8]);
    gld16(gb1 + kk, &lB[2048 + tid * 8]);
    __syncthreads();
    s16x8 af[4], bfr[4];
#pragma unroll
    for (int i = 0; i < 4; ++i)
      af[i] = *(const s16x8*)&lA[(wm + i * 16 + fr) * 32 + fk];
#pragma unroll
    for (int j = 0; j < 4; ++j)
      bfr[j] = *(const s16x8*)&lB[(wn + j * 16 + fr) * 32 + fk];
#pragma unroll
    for (int i = 0; i < 4; ++i)
#pragma unroll
      for (int j = 0; j < 4; ++j)
        acc[i][j] = __builtin_amdgcn_mfma_f32_16x16x32_bf16(af[i], bfr[j], acc[i][j], 0, 0, 0);
    __syncthreads();
  }

  const int er = (lane >> 4) << 2;
  const int ec = lane & 15;
#pragma unroll
  for (int j = 0; j < 4; ++j) {
    int col = n0 + wn + j * 16 + ec;
    if (col >= N) continue;
#pragma unroll
    for (int i = 0; i < 4; ++i) {
#pragma unroll
      for (int r = 0; r < 4; ++r) {
        int row = m0 + wm + i * 16 + er + r;
        size_t off = (size_t)row * ldc + col;
        float v = acc[i][j][r];
        if (bias) v += bias[col];
        Cf[off] = v;
      }
    }
  }
}

// ---------------- split-bf16 GEMM: C = (Ah+Al)*(Bh+Bl)^T (drop Al*Bl) ----------------
__global__ __launch_bounds__(256) void gemm_bt_split(
    const short* __restrict__ Ah, const short* __restrict__ Al,
    const short* __restrict__ Bh, const short* __restrict__ Bl,
    float* __restrict__ Cf, const float* __restrict__ res,
    int N, int K, int ldc)
{
  __shared__ short lAh[4096], lAl[4096], lBh[4096], lBl[4096];
  const int tid  = threadIdx.x;
  const int lane = tid & 63;
  const int wid  = tid >> 6;
  const int m0 = blockIdx.y * 128;
  const int n0 = blockIdx.x * 128;

  const int r0 = tid >> 2;
  const int kc = (tid & 3) << 3;
  const size_t aoff0 = (size_t)(m0 + r0) * K + kc;
  const size_t aoff1 = aoff0 + (size_t)64 * K;
  int nr0 = n0 + r0;      if (nr0 > N - 1) nr0 = N - 1;
  int nr1 = n0 + 64 + r0; if (nr1 > N - 1) nr1 = N - 1;
  const size_t boff0 = (size_t)nr0 * K + kc;
  const size_t boff1 = (size_t)nr1 * K + kc;

  const int fr = lane & 15;
  const int fk = (lane >> 4) << 3;
  const int wm = (wid >> 1) << 6;
  const int wn = (wid & 1) << 6;

  f32x4 acc[4][4] = {};

  for (int kk = 0; kk < K; kk += 32) {
    gld16(Ah + aoff0 + kk, &lAh[tid * 8]);
    gld16(Ah + aoff1 + kk, &lAh[2048 + tid * 8]);
    gld16(Al + aoff0 + kk, &lAl[tid * 8]);
    gld16(Al + aoff1 + kk, &lAl[2048 + tid * 8]);
    gld16(Bh + boff0 + kk, &lBh[tid * 8]);
    gld16(Bh + boff1 + kk, &lBh[2048 + tid * 8]);
    gld16(Bl + boff0 + kk, &lBl[tid * 8]);
    gld16(Bl + boff1 + kk, &lBl[2048 + tid * 8]);
    __syncthreads();
    s16x8 ah[4], al[4], bh[4], bl[4];
#pragma unroll
    for (int i = 0; i < 4; ++i) {
      ah[i] = *(const s16x8*)&lAh[(wm + i * 16 + fr) * 32 + fk];
      al[i] = *(const s16x8*)&lAl[(wm + i * 16 + fr) * 32 + fk];
    }
#pragma unroll
    for (int j = 0; j < 4; ++j) {
      bh[j] = *(const s16x8*)&lBh[(wn + j * 16 + fr) * 32 + fk];
      bl[j] = *(const s16x8*)&lBl[(wn + j * 16 + fr) * 32 + fk];
    }
#pragma unroll
    for (int i = 0; i < 4; ++i)
#pragma unroll
      for (int j = 0; j < 4; ++j) {
        acc[i][j] = __builtin_amdgcn_mfma_f32_16x16x32_bf16(ah[i], bh[j], acc[i][j], 0, 0, 0);
        acc[i][j] = __builtin_amdgcn_mfma_f32_16x16x32_bf16(al[i], bh[j], acc[i][j], 0, 0, 0);
        acc[i][j] = __builtin_amdgcn_mfma_f32_16x16x32_bf16(ah[i], bl[j], acc[i][j], 0, 0, 0);
      }
    __syncthreads();
  }

  const int er = (lane >> 4) << 2;
  const int ec = lane & 15;
#pragma unroll
  for (int j = 0; j < 4; ++j) {
    int col = n0 + wn + j * 16 + ec;
    if (col >= N) continue;
#pragma unroll
    for (int i = 0; i < 4; ++i) {
#pragma unroll
      for (int r = 0; r < 4; ++r) {
        int row = m0 + wm + i * 16 + er + r;
        size_t off = (size_t)row * ldc + col;
        float v = acc[i][j][r];
        if (res) v += res[off];
        Cf[off] = v;
      }
    }
  }
}

// ---------------- small kernels ----------------
__global__ __launch_bounds__(256) void cvt_f2b_k(const float* __restrict__ src,
                                                 short* __restrict__ dst, int n)
{
  for (size_t i = ((size_t)blockIdx.x * 256 + threadIdx.x) * 4; i < (size_t)n;
       i += (size_t)gridDim.x * 1024) {
    f32x4 v = *(const f32x4*)(src + i);
    s16x4 o;
#pragma unroll
    for (int c = 0; c < 4; ++c) o[c] = f2b(v[c]);
    *(s16x4*)(dst + i) = o;
  }
}

__global__ __launch_bounds__(256) void cvt_split_k(const float* __restrict__ src,
                                                   short* __restrict__ hi,
                                                   short* __restrict__ lo, int n)
{
  for (size_t i = ((size_t)blockIdx.x * 256 + threadIdx.x) * 4; i < (size_t)n;
       i += (size_t)gridDim.x * 1024) {
    f32x4 v = *(const f32x4*)(src + i);
    s16x4 h, l;
#pragma unroll
    for (int c = 0; c < 4; ++c) {
      h[c] = f2b(v[c]);
      l[c] = f2b(v[c] - b2f(h[c]));
    }
    *(s16x4*)(hi + i) = h;
    *(s16x4*)(lo + i) = l;
  }
}

__global__ __launch_bounds__(256) void gather_k(const int* __restrict__ tok,
                                                const float* __restrict__ emb,
                                                float* __restrict__ x)
{
  const int row = blockIdx.x;
  const int t = tok[row];
  const f32x4* s = (const f32x4*)(emb + (size_t)t * DIM);
  f32x4* d = (f32x4*)(x + (size_t)row * DIM);
  d[threadIdx.x] = s[threadIdx.x];
}

// rms over 1024, no weight; writes f32 and split-bf16 planes
__global__ __launch_bounds__(256) void rms1024(const float* __restrict__ in,
                                               float* __restrict__ outf,
                                               short* __restrict__ outh,
                                               short* __restrict__ outl)
{
  const int row = blockIdx.x, tid = threadIdx.x;
  f32x4 v = ((const f32x4*)(in + (size_t)row * DIM))[tid];
  float ss = v[0] * v[0] + v[1] * v[1] + v[2] * v[2] + v[3] * v[3];
  for (int o = 32; o; o >>= 1) ss += __shfl_down(ss, o);
  __shared__ float red[4];
  if ((tid & 63) == 0) red[tid >> 6] = ss;
  __syncthreads();
  ss = red[0] + red[1] + red[2] + red[3];
  const float sc = rsqrtf(ss * (1.f / 1024.f) + 1e-6f);
  f32x4 o4 = v * sc;
  ((f32x4*)(outf + (size_t)row * DIM))[tid] = o4;
  s16x4 h, l;
#pragma unroll
  for (int c = 0; c < 4; ++c) {
    h[c] = f2b(o4[c]);
    l[c] = f2b(o4[c] - b2f(h[c]));
  }
  ((s16x4*)(outh + (size_t)row * DIM))[tid] = h;
  ((s16x4*)(outl + (size_t)row * DIM))[tid] = l;
}

// causal depthwise conv (width 4) + bias + silu on xBC slice of zxbcdt
__global__ __launch_bounds__(256) void conv_silu(const float* __restrict__ zx,
                                                 const float* __restrict__ cw,
                                                 const float* __restrict__ cbias,
                                                 float* __restrict__ xbc)
{
  const int t = blockIdx.x;
  const int l = t & (LSEQ - 1);
  for (int c0 = threadIdx.x * 4; c0 < CONVDIM; c0 += 1024) {
    float w[4][4], a[4];
#pragma unroll
    for (int cc = 0; cc < 4; ++cc) {
      f32x4 wv = *(const f32x4*)(cw + (size_t)(c0 + cc) * 4);
      w[cc][0] = wv[0]; w[cc][1] = wv[1]; w[cc][2] = wv[2]; w[cc][3] = wv[3];
      a[cc] = cbias[c0 + cc];
    }
#pragma unroll
    for (int j = 0; j < 4; ++j) {
      int pos = l - 3 + j;
      if (pos < 0) continue;
      f32x4 xv = *(const f32x4*)(zx + (size_t)(t - 3 + j) * DPROJ + DIN + c0);
      a[0] += xv[0] * w[0][j]; a[1] += xv[1] * w[1][j];
      a[2] += xv[2] * w[2][j]; a[3] += xv[3] * w[3][j];
    }
    f32x4 o;
#pragma unroll
    for (int cc = 0; cc < 4; ++cc) o[cc] = a[cc] / (1.f + expf(-a[cc]));
    *(f32x4*)(xbc + (size_t)t * CONVDIM + c0) = o;
  }
}

// dt = softplus(dtraw + bias); a = dt * (-exp(A_log)); ca = cumsum within chunk
__global__ __launch_bounds__(128) void dt_ca(const float* __restrict__ zx,
                                             const float* __restrict__ dtb,
                                             const float* __restrict__ alog,
                                             float* __restrict__ dt,
                                             float* __restrict__ ca)
{
  const int bc = blockIdx.x >> 5, h = blockIdx.x & 31, q = threadIdx.x;
  const int t = bc * 128 + q;
  float raw = zx[(size_t)t * DPROJ + (DIN + CONVDIM) + h] + dtb[h];
  float d = raw > 20.f ? raw : log1pf(expf(raw));
  dt[t * 32 + h] = d;
  float a = -expf(alog[h]) * d;
  __shared__ float s[128];
  s[q] = a;
  __syncthreads();
  for (int off = 1; off < 128; off <<= 1) {
    float v = (q >= off) ? s[q - off] : 0.f;
    __syncthreads();
    s[q] += v;
    __syncthreads();
  }
  ca[(size_t)blockIdx.x * 128 + q] = s[q];
}

// CB[bc][i][j] = sum_n C[i,n]*B[j,n]
__global__ __launch_bounds__(256) void cb_kernel(const float* __restrict__ xbc,
                                                 float* __restrict__ CB)
{
  const int bc = blockIdx.x;
  __shared__ float Bs[128][32], Cs[128][32];
  float acc[8][8] = {};
  const int ti = threadIdx.x >> 4, tj = threadIdx.x & 15;
  for (int n0 = 0; n0 < 128; n0 += 32) {
    __syncthreads();
    for (int e = threadIdx.x; e < 4096; e += 256) {
      int r = e >> 5, c = e & 31;
      const float* row = xbc + (size_t)(bc * 128 + r) * CONVDIM + DIN;
      Bs[r][c] = row[n0 + c];
      Cs[r][c] = row[DSTATE + n0 + c];
    }
    __syncthreads();
    for (int n = 0; n < 32; ++n) {
      float cv[8], bv[8];
#pragma unroll
      for (int ii = 0; ii < 8; ++ii) cv[ii] = Cs[ti * 8 + ii][n];
#pragma unroll
      for (int jj = 0; jj < 8; ++jj) bv[jj] = Bs[tj * 8 + jj][n];
#pragma unroll
      for (int ii = 0; ii < 8; ++ii)
#pragma unroll
        for (int jj = 0; jj < 8; ++jj) acc[ii][jj] += cv[ii] * bv[jj];
    }
  }
  for (int ii = 0; ii < 8; ++ii)
    for (int jj = 0; jj < 8; ++jj)
      CB[(size_t)bc * 16384 + (size_t)(ti * 8 + ii) * 128 + (tj * 8 + jj)] = acc[ii][jj];
}

// y_intra[i][p] = sum_{j<=i} CB[i][j]*exp(ca_i-ca_j)*dt_j*x[j][p]
__global__ __launch_bounds__(256) void yintra(const float* __restrict__ xbc,
                                              const float* __restrict__ dt,
                                              const float* __restrict__ ca,
                                              const float* __restrict__ CB,
                                              float* __restrict__ ybuf)
{
  const int bc = blockIdx.x >> 5, h = blockIdx.x & 31;
  __shared__ float xdt[128][64];
  __shared__ float cas[128];
  const int tid = threadIdx.x;
  if (tid < 128) cas[tid] = ca[(size_t)blockIdx.x * 128 + tid];
  for (int e = tid * 4; e < 8192; e += 1024) {
    int j = e >> 6, p = e & 63;
    f32x4 xv = *(const f32x4*)(xbc + (size_t)(bc * 128 + j) * CONVDIM + h * 64 + p);
    float dj = dt[(size_t)(bc * 128 + j) * 32 + h];
    xv *= dj;
    *(f32x4*)&xdt[j][p] = xv;
  }
  __syncthreads();
  const int i = tid >> 1, pb = (tid & 1) * 32;
  const float cai = cas[i];
  const float* cbrow = CB + (size_t)bc * 16384 + (size_t)i * 128;
  f32x4 acc[8] = {};
  for (int j = 0; j <= i; ++j) {
    float coeff = cbrow[j] * expf(cai - cas[j]);
    const f32x4* xr = (const f32x4*)&xdt[j][pb];
#pragma unroll
    for (int q = 0; q < 8; ++q) acc[q] += coeff * xr[q];
  }
  float* yo = ybuf + (size_t)(bc * 128 + i) * DIN + h * 64 + pb;
#pragma unroll
  for (int q = 0; q < 8; ++q) *(f32x4*)(yo + q * 4) = acc[q];
}

// states[n][p] = sum_j exp(ca_last-ca_j)*dt_j*B[j][n]*x[j][p]   (layout [bc][h][n][p])
__global__ __launch_bounds__(256) void states_k(const float* __restrict__ xbc,
                                                const float* __restrict__ dt,
                                                const float* __restrict__ ca,
                                                float* __restrict__ states)
{
  const int bc = blockIdx.x >> 5, h = blockIdx.x & 31;
  __shared__ float xw[128][64];
  __shared__ float Bs[32][128];
  __shared__ float warr[128];
  const int tid = threadIdx.x;
  if (tid < 128) {
    float cv = ca[(size_t)blockIdx.x * 128 + tid];
    float clast = ca[(size_t)blockIdx.x * 128 + 127];
    warr[tid] = expf(clast - cv) * dt[(size_t)(bc * 128 + tid) * 32 + h];
  }
  __syncthreads();
  for (int e = tid * 4; e < 8192; e += 1024) {
    int j = e >> 6, p = e & 63;
    f32x4 xv = *(const f32x4*)(xbc + (size_t)(bc * 128 + j) * CONVDIM + h * 64 + p);
    *(f32x4*)&xw[j][p] = xv * warr[j];
  }
  const int w = tid >> 6, p = tid & 63;
  f32x4 acc[8] = {};
  for (int jc = 0; jc < 128; jc += 32) {
    __syncthreads();
    for (int e = tid * 4; e < 4096; e += 1024) {
      int j = e >> 7, n = e & 127;
      *(f32x4*)&Bs[j][n] =
          *(const f32x4*)(xbc + (size_t)(bc * 128 + jc + j) * CONVDIM + DIN + n);
    }
    __syncthreads();
    for (int j = 0; j < 32; ++j) {
      float xv = xw[jc + j][p];
      const f32x4* br = (const f32x4*)&Bs[j][w * 32];
#pragma unroll
      for (int q = 0; q < 8; ++q) acc[q] += xv * br[q];
    }
  }
  float* sb = states + (size_t)blockIdx.x * 8192;
#pragma unroll
  for (int q = 0; q < 8; ++q)
#pragma unroll
    for (int c = 0; c < 4; ++c) {
      int n = w * 32 + q * 4 + c;
      sb[(size_t)n * 64 + p] = acc[q][c];
    }
}

// inter-chunk scan: states[bc] := s_prev ; s = s*cd + states
__global__ __launch_bounds__(256) void scan_k(const float* __restrict__ ca,
                                              float* __restrict__ states)
{
  const int b = blockIdx.x >> 10, h = (blockIdx.x >> 5) & 31, seg = blockIdx.x & 31;
  const int e = seg * 256 + threadIdx.x;
  float s = 0.f;
  for (int c = 0; c < CPB; ++c) {
    int bc = b * CPB + c;
    float cd = expf(ca[(size_t)(bc * 32 + h) * 128 + 127]);
    size_t idx = (size_t)(bc * 32 + h) * 8192 + e;
    float v = states[idx];
    states[idx] = s;
    s = s * cd + v;
  }
}

// y += exp(ca_i)*C[i,:]·s_prev[:, p] + D_h * x
__global__ __launch_bounds__(256) void yinter(const float* __restrict__ xbc,
                                              const float* __restrict__ ca,
                                              const float* __restrict__ Dvec,
                                              const float* __restrict__ states,
                                              float* __restrict__ ybuf)
{
  const int bc = blockIdx.x >> 5, h = blockIdx.x & 31;
  __shared__ float sp[128 * 64];
  __shared__ float cas[128];
  const int tid = threadIdx.x;
  if (tid < 128) cas[tid] = ca[(size_t)blockIdx.x * 128 + tid];
  const float* sg = states + (size_t)blockIdx.x * 8192;
  for (int e = tid * 4; e < 8192; e += 1024)
    *(f32x4*)&sp[e] = *(const f32x4*)(sg + e);
  __syncthreads();
  const int i = tid >> 1, pb = (tid & 1) * 32;
  const float* crow = xbc + (size_t)(bc * 128 + i) * CONVDIM + DIN + DSTATE;
  f32x4 acc[8] = {};
  for (int n = 0; n < 128; ++n) {
    float cn = crow[n];
    const f32x4* sr = (const f32x4*)&sp[n * 64 + pb];
#pragma unroll
    for (int q = 0; q < 8; ++q) acc[q] += cn * sr[q];
  }
  const float ei = expf(cas[i]);
  const float dh = Dvec[h];
  const int tg = bc * 128 + i;
  float* yo = ybuf + (size_t)tg * DIN + h * 64 + pb;
  const float* xv = xbc + (size_t)tg * CONVDIM + h * 64 + pb;
#pragma unroll
  for (int q = 0; q < 8; ++q) {
    f32x4 y = *(const f32x4*)(yo + q * 4);
    f32x4 x4 = *(const f32x4*)(xv + q * 4);
    y += ei * acc[q] + dh * x4;
    *(f32x4*)(yo + q * 4) = y;
  }
}

// yg = y*silu(z); rms(2048) * mnorm_w -> split bf16 planes (stride DIN)
__global__ __launch_bounds__(256) void gate_rms(const float* __restrict__ ybuf,
                                                const float* __restrict__ zx,
                                                const float* __restrict__ nw,
                                                short* __restrict__ outh,
                                                short* __restrict__ outl)
{
  const int row = blockIdx.x, tid = threadIdx.x;
  const float* yr = ybuf + (size_t)row * DIN;
  const float* zr = zx + (size_t)row * DPROJ;
  f32x4 y0 = *(const f32x4*)(yr + tid * 4);
  f32x4 y1 = *(const f32x4*)(yr + 1024 + tid * 4);
  f32x4 z0 = *(const f32x4*)(zr + tid * 4);
  f32x4 z1 = *(const f32x4*)(zr + 1024 + tid * 4);
  f32x4 g0, g1;
#pragma unroll
  for (int c = 0; c < 4; ++c) {
    g0[c] = y0[c] * (z0[c] / (1.f + expf(-z0[c])));
    g1[c] = y1[c] * (z1[c] / (1.f + expf(-z1[c])));
  }
  float ss = 0.f;
#pragma unroll
  for (int c = 0; c < 4; ++c) ss += g0[c] * g0[c] + g1[c] * g1[c];
  for (int o = 32; o; o >>= 1) ss += __shfl_down(ss, o);
  __shared__ float red[4];
  if ((tid & 63) == 0) red[tid >> 6] = ss;
  __syncthreads();
  ss = red[0] + red[1] + red[2] + red[3];
  const float sc = rsqrtf(ss * (1.f / 2048.f) + 1e-6f);
  f32x4 w0 = *(const f32x4*)(nw + tid * 4);
  f32x4 w1 = *(const f32x4*)(nw + 1024 + tid * 4);
  s16x4 h0, h1, l0, l1;
#pragma unroll
  for (int c = 0; c < 4; ++c) {
    float a0 = g0[c] * sc * w0[c];
    float a1 = g1[c] * sc * w1[c];
    h0[c] = f2b(a0); l0[c] = f2b(a0 - b2f(h0[c]));
    h1[c] = f2b(a1); l1[c] = f2b(a1 - b2f(h1[c]));
  }
  *(s16x4*)(outh + (size_t)row * DIN + tid * 4) = h0;
  *(s16x4*)(outh + (size_t)row * DIN + 1024 + tid * 4) = h1;
  *(s16x4*)(outl + (size_t)row * DIN + tid * 4) = l0;
  *(s16x4*)(outl + (size_t)row * DIN + 1024 + tid * 4) = l1;
}

// G = split(U*V) from f32 UV [4096][8192] -> planes stride FFN
__global__ __launch_bounds__(256) void gmul(const float* __restrict__ UV,
                                            short* __restrict__ Gh,
                                            short* __restrict__ Gl)
{
  size_t e = ((size_t)blockIdx.x * 256 + threadIdx.x) * 4;
  int t = (int)(e >> 12), f = (int)(e & 4095);
  f32x4 u = *(const f32x4*)&UV[(size_t)t * 8192 + f];
  f32x4 v = *(const f32x4*)&UV[(size_t)t * 8192 + 4096 + f];
  s16x4 h, l;
#pragma unroll
  for (int c = 0; c < 4; ++c) {
    float g = u[c] * v[c];
    h[c] = f2b(g);
    l[c] = f2b(g - b2f(h[c]));
  }
  *(s16x4*)&Gh[e] = h;
  *(s16x4*)&Gl[e] = l;
}

// ---------------- launcher ----------------
static inline void launch_gemm_split(const short* Ah, const short* Al,
                                     const short* Bh, const short* Bl,
                                     float* Cf, const float* res,
                                     int M, int N, int K, int ldc, hipStream_t st)
{
  dim3 g((N + 127) / 128, M / 128);
  gemm_bt_split<<<g, 256, 0, st>>>(Ah, Al, Bh, Bl, Cf, res, N, K, ldc);
}

extern "C" void kernel_launch(void* const* d_in, const int* in_sizes, int n_in,
                              void* d_out, int out_size, void* d_ws, size_t ws_size,
                              hipStream_t stream)
{
  (void)in_sizes; (void)n_in; (void)out_size; (void)ws_size;
  const int*   tokens = (const int*)d_in[0];
  const float* emb    = (const float*)d_in[1];
  const float* lmb    = (const float*)d_in[2];
  const float* inw    = (const float*)d_in[3];
  const float* cw     = (const float*)d_in[4];
  const float* cbias  = (const float*)d_in[5];
  const float* dtb    = (const float*)d_in[6];
  const float* alog   = (const float*)d_in[7];
  const float* Dvec   = (const float*)d_in[8];
  const float* nw     = (const float*)d_in[9];
  const float* outw   = (const float*)d_in[10];
  const float* uw     = (const float*)d_in[11];
  const float* vw     = (const float*)d_in[12];
  const float* ow     = (const float*)d_in[13];

  char* ws = (char*)d_ws;
  size_t off = 0;
  auto alloc = [&](size_t bytes) { void* p = ws + off; off += (bytes + 255) & ~(size_t)255; return p; };
  short* emb_b  = (short*)alloc((size_t)VOCAB * DIM * 2);          // 65.5 MB
  // per-layer shared split weight planes (converted in-loop)
  short* w_inh  = (short*)alloc((size_t)DPROJ * DIM * 2);          //  9.0 MB
  short* w_inl  = (short*)alloc((size_t)DPROJ * DIM * 2);
  short* w_outh = (short*)alloc((size_t)DIM * DIN * 2);            //  4.2 MB
  short* w_outl = (short*)alloc((size_t)DIM * DIN * 2);
  short* w_uvh  = (short*)alloc((size_t)2 * FFN * DIM * 2);        // 16.8 MB
  short* w_uvl  = (short*)alloc((size_t)2 * FFN * DIM * 2);
  short* w_oh   = (short*)alloc((size_t)DIM * FFN * 2);            //  8.4 MB
  short* w_ol   = (short*)alloc((size_t)DIM * FFN * 2);
  float* xbuf   = (float*)alloc((size_t)NTOK * DIM * 4);
  float* xn     = (float*)alloc((size_t)NTOK * DIM * 4);
  short* xnh    = (short*)alloc((size_t)NTOK * DIM * 2);
  short* xnl    = (short*)alloc((size_t)NTOK * DIM * 2);
  short* xnb    = (short*)alloc((size_t)NTOK * DIM * 2);
  float* dtbuf  = (float*)alloc((size_t)NTOK * NH * 4);
  float* cabuf  = (float*)alloc((size_t)NCHUNK * NH * QLEN * 4);
  float* CBbuf  = (float*)alloc((size_t)NCHUNK * QLEN * QLEN * 4);
  short* abh    = (short*)alloc((size_t)NTOK * FFN * 2);           // 33.6 MB
  short* abl    = (short*)alloc((size_t)NTOK * FFN * 2);           // 33.6 MB

  // big transients live in d_out (fully overwritten by the final GEMM)
  char* ob = (char*)d_out;
  float* states = (float*)(ob);                    // 134,217,728 B
  float* UVb    = (float*)(ob + 134217728);        // 134,217,728 B (f32)
  float* zxb    = (float*)(ob + 268435456);        //  71,827,456 B
  float* xbc    = (float*)(ob + 340262912);        //  37,748,736 B
  float* ybuf   = (float*)(ob + 378011648);        //  33,554,432 B (end 411,566,080)

  cvt_f2b_k<<<4096, 256, 0, stream>>>(emb, emb_b, VOCAB * DIM);
  gather_k<<<NTOK, 256, 0, stream>>>(tokens, emb, xbuf);

  for (int it = 0; it < 2 * NLAYER; ++it) {
    const int li = it >> 1;
    if ((it & 1) == 0) {
      // convert this layer's weights to split planes
      cvt_split_k<<<2048, 256, 0, stream>>>(inw + (size_t)li * DPROJ * DIM, w_inh, w_inl, DPROJ * DIM);
      cvt_split_k<<<1024, 256, 0, stream>>>(outw + (size_t)li * DIM * DIN, w_outh, w_outl, DIM * DIN);
      cvt_split_k<<<2048, 256, 0, stream>>>(uw + (size_t)li * FFN * DIM, w_uvh, w_uvl, FFN * DIM);
      cvt_split_k<<<2048, 256, 0, stream>>>(vw + (size_t)li * FFN * DIM,
                                            w_uvh + (size_t)FFN * DIM, w_uvl + (size_t)FFN * DIM, FFN * DIM);
      cvt_split_k<<<2048, 256, 0, stream>>>(ow + (size_t)li * DIM * FFN, w_oh, w_ol, DIM * FFN);
    }
    // x = rms(x) ; mamba
    rms1024<<<NTOK, 256, 0, stream>>>(xbuf, xn, xnh, xnl);
    launch_gemm_split(xnh, xnl, w_inh, w_inl, zxb, nullptr, NTOK, DPROJ, DIM, DPROJ, stream);
    conv_silu<<<NTOK, 256, 0, stream>>>(zxb, cw + (size_t)li * CONVDIM * DCONV,
                                        cbias + (size_t)li * CONVDIM, xbc);
    dt_ca<<<NCHUNK * NH, 128, 0, stream>>>(zxb, dtb + li * NH, alog + li * NH, dtbuf, cabuf);
    cb_kernel<<<NCHUNK, 256, 0, stream>>>(xbc, CBbuf);
    yintra<<<NCHUNK * NH, 256, 0, stream>>>(xbc, dtbuf, cabuf, CBbuf, ybuf);
    states_k<<<NCHUNK * NH, 256, 0, stream>>>(xbc, dtbuf, cabuf, states);
    scan_k<<<2048, 256, 0, stream>>>(cabuf, states);
    yinter<<<NCHUNK * NH, 256, 0, stream>>>(xbc, cabuf, Dvec + li * NH, states, ybuf);
    gate_rms<<<NTOK, 256, 0, stream>>>(ybuf, zxb, nw + (size_t)li * DIN, abh, abl);
    launch_gemm_split(abh, abl, w_outh, w_outl, xbuf, xn, NTOK, DIM, DIN, DIM, stream);
    // x = rms(x) ; gated FFN
    rms1024<<<NTOK, 256, 0, stream>>>(xbuf, xn, xnh, xnl);
    launch_gemm_split(xnh, xnl, w_uvh, w_uvl, UVb, nullptr, NTOK, 2 * FFN, DIM, 2 * FFN, stream);
    gmul<<<16384, 256, 0, stream>>>(UVb, abh, abl);
    launch_gemm_split(abh, abl, w_oh, w_ol, xbuf, xn, NTOK, DIM, FFN, DIM, stream);
  }

  // lm head (single bf16 is plenty accurate here)
  cvt_f2b_k<<<4096, 256, 0, stream>>>(xbuf, xnb, NTOK * DIM);
  {
    dim3 g((VOCAB + 127) / 128, NTOK / 128);
    gemm_bt<<<g, 256, 0, stream>>>(xnb, emb_b, (float*)d_out, lmb, VOCAB, DIM, VOCAB);
  }
}

// Round 3
// 7779.931 us; speedup vs baseline: 1.2008x; 1.2008x over previous
//
#include <hip/hip_runtime.h>
#include <hip/hip_bf16.h>

// ---------------- problem constants ----------------
#define BSZ 2
#define LSEQ 2048
#define DIM 1024
#define VOCAB 32000
#define NLAYER 4
#define DSTATE 128
#define DCONV 4
#define HEADDIM 64
#define DIN 2048
#define NH 32
#define CONVDIM 2304          // DIN + 2*DSTATE
#define DPROJ 4384            // 2*DIN + 2*DSTATE + NH
#define FFN 4096
#define QLEN 128
#define NTOK 4096             // BSZ*LSEQ
#define NCHUNK 32             // NTOK/QLEN
#define CPB 16                // chunks per batch

using f32x4 = __attribute__((ext_vector_type(4))) float;
using s16x4 = __attribute__((ext_vector_type(4))) short;
using s16x8 = __attribute__((ext_vector_type(8))) short;

__device__ __forceinline__ short f2b(float f) {
  unsigned u = __builtin_bit_cast(unsigned, f);
  u += 0x7FFFu + ((u >> 16) & 1u);
  return (short)(u >> 16);
}
__device__ __forceinline__ float b2f(short s) {
  unsigned u = ((unsigned)(unsigned short)s) << 16;
  return __builtin_bit_cast(float, u);
}
__device__ __forceinline__ void gld16(const short* g, short* l) {
  __builtin_amdgcn_global_load_lds(
      (const __attribute__((address_space(1))) unsigned int*)g,
      (__attribute__((address_space(3))) unsigned int*)l, 16, 0, 0);
}

// Tile swizzle: XCD-contiguous + column-chunked (8 bx per chunk, sweep all by)
// so each XCD keeps a <=4MB B-panel chunk L2-resident across the M sweep.
__device__ __forceinline__ void swz_tiles(int& bx, int& by) {
  const int nx = gridDim.x, ny = gridDim.y;
  const int nwg = nx * ny;
  int bid = blockIdx.y * nx + blockIdx.x;
  if ((nwg & 7) == 0) bid = (bid & 7) * (nwg >> 3) + (bid >> 3);
  const int CW = 8;
  const int nchx = nx / CW;
  const int per = CW * ny;
  const int ch = bid / per;
  if (ch < nchx) {
    int wi = bid - ch * per;
    bx = ch * CW + (wi & (CW - 1));
    by = wi / CW;
  } else {
    int tb = bid - nchx * per;
    int tw = nx - nchx * CW;          // >0 whenever this branch is reached
    bx = nchx * CW + (tb % tw);
    by = tb / tw;
  }
}

// ---------------- single-bf16 GEMM (lm-head): C = A * B^T + bias ----------------
__global__ __launch_bounds__(256) void gemm_bt(
    const short* __restrict__ A, const short* __restrict__ B,
    float* __restrict__ Cf, const float* __restrict__ bias,
    int N, int K, int ldc)
{
  __shared__ short lA[4096];
  __shared__ short lB[4096];
  const int tid  = threadIdx.x;
  const int lane = tid & 63;
  const int wid  = tid >> 6;
  int bx, by; swz_tiles(bx, by);
  const int m0 = by * 128;
  const int n0 = bx * 128;

  const int r0 = tid >> 2;
  const int kc = (tid & 3) << 3;
  const short* ga0 = A + (size_t)(m0 + r0) * K + kc;
  const short* ga1 = ga0 + (size_t)64 * K;
  int nr0 = n0 + r0;      if (nr0 > N - 1) nr0 = N - 1;
  int nr1 = n0 + 64 + r0; if (nr1 > N - 1) nr1 = N - 1;
  const short* gb0 = B + (size_t)nr0 * K + kc;
  const short* gb1 = B + (size_t)nr1 * K + kc;

  const int fr = lane & 15;
  const int fk = (lane >> 4) << 3;
  const int wm = (wid >> 1) << 6;
  const int wn = (wid & 1) << 6;

  f32x4 acc[4][4] = {};

  for (int kk = 0; kk < K; kk += 32) {
    gld16(ga0 + kk, &lA[tid * 8]);
    gld16(ga1 + kk, &lA[2048 + tid * 8]);
    gld16(gb0 + kk, &lB[tid * 8]);
    gld16(gb1 + kk, &lB[2048 + tid * 8]);
    __syncthreads();
    s16x8 af[4], bfr[4];
#pragma unroll
    for (int i = 0; i < 4; ++i)
      af[i] = *(const s16x8*)&lA[(wm + i * 16 + fr) * 32 + fk];
#pragma unroll
    for (int j = 0; j < 4; ++j)
      bfr[j] = *(const s16x8*)&lB[(wn + j * 16 + fr) * 32 + fk];
#pragma unroll
    for (int i = 0; i < 4; ++i)
#pragma unroll
      for (int j = 0; j < 4; ++j)
        acc[i][j] = __builtin_amdgcn_mfma_f32_16x16x32_bf16(af[i], bfr[j], acc[i][j], 0, 0, 0);
    __syncthreads();
  }

  const int er = (lane >> 4) << 2;
  const int ec = lane & 15;
#pragma unroll
  for (int j = 0; j < 4; ++j) {
    int col = n0 + wn + j * 16 + ec;
    if (col >= N) continue;
#pragma unroll
    for (int i = 0; i < 4; ++i) {
#pragma unroll
      for (int r = 0; r < 4; ++r) {
        int row = m0 + wm + i * 16 + er + r;
        size_t off = (size_t)row * ldc + col;
        float v = acc[i][j][r];
        if (bias) v += bias[col];
        Cf[off] = v;
      }
    }
  }
}

// ---------------- split-bf16 GEMM: C = (Ah+Al)*(Bh+Bl)^T (drop Al*Bl) ----------------
// BN = 128 (waves 2x2, wave 64x64) or 64 (waves 2x2, wave 64x32).
template <int BN>
__global__ __launch_bounds__(256) void gemm_bt_split(
    const short* __restrict__ Ah, const short* __restrict__ Al,
    const short* __restrict__ Bh, const short* __restrict__ Bl,
    float* __restrict__ Cf, const float* __restrict__ res,
    int N, int K, int ldc)
{
  constexpr int JN = BN / 32;   // j-fragments per wave
  __shared__ short lAh[4096], lAl[4096];
  __shared__ short lBh[BN * 32], lBl[BN * 32];
  const int tid  = threadIdx.x;
  const int lane = tid & 63;
  const int wid  = tid >> 6;
  int bx, by; swz_tiles(bx, by);
  const int m0 = by * 128;
  const int n0 = bx * BN;

  const int r0 = tid >> 2;
  const int kc = (tid & 3) << 3;
  const size_t aoff0 = (size_t)(m0 + r0) * K + kc;
  const size_t aoff1 = aoff0 + (size_t)64 * K;
  int nr0 = n0 + r0;      if (nr0 > N - 1) nr0 = N - 1;
  const size_t boff0 = (size_t)nr0 * K + kc;
  size_t boff1 = 0;
  if constexpr (BN == 128) {
    int nr1 = n0 + 64 + r0; if (nr1 > N - 1) nr1 = N - 1;
    boff1 = (size_t)nr1 * K + kc;
  }

  const int fr = lane & 15;
  const int fk = (lane >> 4) << 3;
  const int wm = (wid >> 1) << 6;
  const int wn = (wid & 1) * (BN / 2);

  f32x4 acc[4][JN] = {};

  for (int kk = 0; kk < K; kk += 32) {
    gld16(Ah + aoff0 + kk, &lAh[tid * 8]);
    gld16(Ah + aoff1 + kk, &lAh[2048 + tid * 8]);
    gld16(Al + aoff0 + kk, &lAl[tid * 8]);
    gld16(Al + aoff1 + kk, &lAl[2048 + tid * 8]);
    gld16(Bh + boff0 + kk, &lBh[tid * 8]);
    gld16(Bl + boff0 + kk, &lBl[tid * 8]);
    if constexpr (BN == 128) {
      gld16(Bh + boff1 + kk, &lBh[2048 + tid * 8]);
      gld16(Bl + boff1 + kk, &lBl[2048 + tid * 8]);
    }
    __syncthreads();
    s16x8 ah[4], al[4], bh[JN], bl[JN];
#pragma unroll
    for (int i = 0; i < 4; ++i) {
      ah[i] = *(const s16x8*)&lAh[(wm + i * 16 + fr) * 32 + fk];
      al[i] = *(const s16x8*)&lAl[(wm + i * 16 + fr) * 32 + fk];
    }
#pragma unroll
    for (int j = 0; j < JN; ++j) {
      bh[j] = *(const s16x8*)&lBh[(wn + j * 16 + fr) * 32 + fk];
      bl[j] = *(const s16x8*)&lBl[(wn + j * 16 + fr) * 32 + fk];
    }
#pragma unroll
    for (int i = 0; i < 4; ++i)
#pragma unroll
      for (int j = 0; j < JN; ++j) {
        acc[i][j] = __builtin_amdgcn_mfma_f32_16x16x32_bf16(ah[i], bh[j], acc[i][j], 0, 0, 0);
        acc[i][j] = __builtin_amdgcn_mfma_f32_16x16x32_bf16(al[i], bh[j], acc[i][j], 0, 0, 0);
        acc[i][j] = __builtin_amdgcn_mfma_f32_16x16x32_bf16(ah[i], bl[j], acc[i][j], 0, 0, 0);
      }
    __syncthreads();
  }

  const int er = (lane >> 4) << 2;
  const int ec = lane & 15;
#pragma unroll
  for (int j = 0; j < JN; ++j) {
    int col = n0 + wn + j * 16 + ec;
    if (col >= N) continue;
#pragma unroll
    for (int i = 0; i < 4; ++i) {
#pragma unroll
      for (int r = 0; r < 4; ++r) {
        int row = m0 + wm + i * 16 + er + r;
        size_t off = (size_t)row * ldc + col;
        float v = acc[i][j][r];
        if (res) v += res[off];
        Cf[off] = v;
      }
    }
  }
}

// ---------------- fused UV GEMM: G = split(bf16((A*U^T) .* (A*V^T))) ----------------
// B planes are packed [2*FFN][DIM]: rows [0,FFN)=U, [FFN,2*FFN)=V.
__global__ __launch_bounds__(256) void gemm_uv_split(
    const short* __restrict__ Ah, const short* __restrict__ Al,
    const short* __restrict__ Bh, const short* __restrict__ Bl,
    short* __restrict__ Gh, short* __restrict__ Gl)
{
  __shared__ short lAh[4096], lAl[4096], lBh[4096], lBl[4096];
  const int tid  = threadIdx.x;
  const int lane = tid & 63;
  const int wid  = tid >> 6;
  int bx, by; swz_tiles(bx, by);
  const int m0 = by * 128;
  const int n0 = bx * 128;
  const int K = DIM;

  const int r0 = tid >> 2;
  const int kc = (tid & 3) << 3;
  const size_t aoff0 = (size_t)(m0 + r0) * K + kc;
  const size_t aoff1 = aoff0 + (size_t)64 * K;

  const int fr = lane & 15;
  const int fk = (lane >> 4) << 3;
  const int wm = (wid >> 1) << 6;
  const int wn = (wid & 1) << 6;

  f32x4 accu[4][4] = {}, accv[4][4] = {};

  auto half_loop = [&](size_t b0, size_t b1, f32x4 (&acc)[4][4]) {
    for (int kk = 0; kk < K; kk += 32) {
      gld16(Ah + aoff0 + kk, &lAh[tid * 8]);
      gld16(Ah + aoff1 + kk, &lAh[2048 + tid * 8]);
      gld16(Al + aoff0 + kk, &lAl[tid * 8]);
      gld16(Al + aoff1 + kk, &lAl[2048 + tid * 8]);
      gld16(Bh + b0 + kk, &lBh[tid * 8]);
      gld16(Bh + b1 + kk, &lBh[2048 + tid * 8]);
      gld16(Bl + b0 + kk, &lBl[tid * 8]);
      gld16(Bl + b1 + kk, &lBl[2048 + tid * 8]);
      __syncthreads();
      s16x8 ah[4], al[4], bh[4], bl[4];
#pragma unroll
      for (int i = 0; i < 4; ++i) {
        ah[i] = *(const s16x8*)&lAh[(wm + i * 16 + fr) * 32 + fk];
        al[i] = *(const s16x8*)&lAl[(wm + i * 16 + fr) * 32 + fk];
      }
#pragma unroll
      for (int j = 0; j < 4; ++j) {
        bh[j] = *(const s16x8*)&lBh[(wn + j * 16 + fr) * 32 + fk];
        bl[j] = *(const s16x8*)&lBl[(wn + j * 16 + fr) * 32 + fk];
      }
#pragma unroll
      for (int i = 0; i < 4; ++i)
#pragma unroll
        for (int j = 0; j < 4; ++j) {
          acc[i][j] = __builtin_amdgcn_mfma_f32_16x16x32_bf16(ah[i], bh[j], acc[i][j], 0, 0, 0);
          acc[i][j] = __builtin_amdgcn_mfma_f32_16x16x32_bf16(al[i], bh[j], acc[i][j], 0, 0, 0);
          acc[i][j] = __builtin_amdgcn_mfma_f32_16x16x32_bf16(ah[i], bl[j], acc[i][j], 0, 0, 0);
        }
      __syncthreads();
    }
  };

  const size_t bu0 = (size_t)(n0 + r0) * K + kc;
  const size_t bu1 = bu0 + (size_t)64 * K;
  const size_t bv0 = (size_t)(FFN + n0 + r0) * K + kc;
  const size_t bv1 = bv0 + (size_t)64 * K;
  half_loop(bu0, bu1, accu);
  half_loop(bv0, bv1, accv);

  const int er = (lane >> 4) << 2;
  const int ec = lane & 15;
#pragma unroll
  for (int j = 0; j < 4; ++j) {
    int col = n0 + wn + j * 16 + ec;
#pragma unroll
    for (int i = 0; i < 4; ++i) {
#pragma unroll
      for (int r = 0; r < 4; ++r) {
        int row = m0 + wm + i * 16 + er + r;
        size_t off = (size_t)row * FFN + col;
        float g = accu[i][j][r] * accv[i][j][r];
        short h = f2b(g);
        Gh[off] = h;
        Gl[off] = f2b(g - b2f(h));
      }
    }
  }
}

// ---------------- small kernels ----------------
__global__ __launch_bounds__(256) void cvt_f2b_k(const float* __restrict__ src,
                                                 short* __restrict__ dst, int n)
{
  for (size_t i = ((size_t)blockIdx.x * 256 + threadIdx.x) * 4; i < (size_t)n;
       i += (size_t)gridDim.x * 1024) {
    f32x4 v = *(const f32x4*)(src + i);
    s16x4 o;
#pragma unroll
    for (int c = 0; c < 4; ++c) o[c] = f2b(v[c]);
    *(s16x4*)(dst + i) = o;
  }
}

__global__ __launch_bounds__(256) void cvt_split_k(const float* __restrict__ src,
                                                   short* __restrict__ hi,
                                                   short* __restrict__ lo, int n)
{
  for (size_t i = ((size_t)blockIdx.x * 256 + threadIdx.x) * 4; i < (size_t)n;
       i += (size_t)gridDim.x * 1024) {
    f32x4 v = *(const f32x4*)(src + i);
    s16x4 h, l;
#pragma unroll
    for (int c = 0; c < 4; ++c) {
      h[c] = f2b(v[c]);
      l[c] = f2b(v[c] - b2f(h[c]));
    }
    *(s16x4*)(hi + i) = h;
    *(s16x4*)(lo + i) = l;
  }
}

__global__ __launch_bounds__(256) void gather_k(const int* __restrict__ tok,
                                                const float* __restrict__ emb,
                                                float* __restrict__ x)
{
  const int row = blockIdx.x;
  const int t = tok[row];
  const f32x4* s = (const f32x4*)(emb + (size_t)t * DIM);
  f32x4* d = (f32x4*)(x + (size_t)row * DIM);
  d[threadIdx.x] = s[threadIdx.x];
}

// rms over 1024, no weight; writes f32 and split-bf16 planes
__global__ __launch_bounds__(256) void rms1024(const float* __restrict__ in,
                                               float* __restrict__ outf,
                                               short* __restrict__ outh,
                                               short* __restrict__ outl)
{
  const int row = blockIdx.x, tid = threadIdx.x;
  f32x4 v = ((const f32x4*)(in + (size_t)row * DIM))[tid];
  float ss = v[0] * v[0] + v[1] * v[1] + v[2] * v[2] + v[3] * v[3];
  for (int o = 32; o; o >>= 1) ss += __shfl_down(ss, o);
  __shared__ float red[4];
  if ((tid & 63) == 0) red[tid >> 6] = ss;
  __syncthreads();
  ss = red[0] + red[1] + red[2] + red[3];
  const float sc = rsqrtf(ss * (1.f / 1024.f) + 1e-6f);
  f32x4 o4 = v * sc;
  ((f32x4*)(outf + (size_t)row * DIM))[tid] = o4;
  s16x4 h, l;
#pragma unroll
  for (int c = 0; c < 4; ++c) {
    h[c] = f2b(o4[c]);
    l[c] = f2b(o4[c] - b2f(h[c]));
  }
  ((s16x4*)(outh + (size_t)row * DIM))[tid] = h;
  ((s16x4*)(outl + (size_t)row * DIM))[tid] = l;
}

// causal depthwise conv (width 4) + bias + silu on xBC slice of zxbcdt
__global__ __launch_bounds__(256) void conv_silu(const float* __restrict__ zx,
                                                 const float* __restrict__ cw,
                                                 const float* __restrict__ cbias,
                                                 float* __restrict__ xbc)
{
  const int t = blockIdx.x;
  const int l = t & (LSEQ - 1);
  for (int c0 = threadIdx.x * 4; c0 < CONVDIM; c0 += 1024) {
    float w[4][4], a[4];
#pragma unroll
    for (int cc = 0; cc < 4; ++cc) {
      f32x4 wv = *(const f32x4*)(cw + (size_t)(c0 + cc) * 4);
      w[cc][0] = wv[0]; w[cc][1] = wv[1]; w[cc][2] = wv[2]; w[cc][3] = wv[3];
      a[cc] = cbias[c0 + cc];
    }
#pragma unroll
    for (int j = 0; j < 4; ++j) {
      int pos = l - 3 + j;
      if (pos < 0) continue;
      f32x4 xv = *(const f32x4*)(zx + (size_t)(t - 3 + j) * DPROJ + DIN + c0);
      a[0] += xv[0] * w[0][j]; a[1] += xv[1] * w[1][j];
      a[2] += xv[2] * w[2][j]; a[3] += xv[3] * w[3][j];
    }
    f32x4 o;
#pragma unroll
    for (int cc = 0; cc < 4; ++cc) o[cc] = a[cc] / (1.f + expf(-a[cc]));
    *(f32x4*)(xbc + (size_t)t * CONVDIM + c0) = o;
  }
}

// dt = softplus(dtraw + bias); a = dt * (-exp(A_log)); ca = cumsum within chunk
__global__ __launch_bounds__(128) void dt_ca(const float* __restrict__ zx,
                                             const float* __restrict__ dtb,
                                             const float* __restrict__ alog,
                                             float* __restrict__ dt,
                                             float* __restrict__ ca)
{
  const int bc = blockIdx.x >> 5, h = blockIdx.x & 31, q = threadIdx.x;
  const int t = bc * 128 + q;
  float raw = zx[(size_t)t * DPROJ + (DIN + CONVDIM) + h] + dtb[h];
  float d = raw > 20.f ? raw : log1pf(expf(raw));
  dt[t * 32 + h] = d;
  float a = -expf(alog[h]) * d;
  __shared__ float s[128];
  s[q] = a;
  __syncthreads();
  for (int off = 1; off < 128; off <<= 1) {
    float v = (q >= off) ? s[q - off] : 0.f;
    __syncthreads();
    s[q] += v;
    __syncthreads();
  }
  ca[(size_t)blockIdx.x * 128 + q] = s[q];
}

// CB[bc][i][j] = sum_n C[i,n]*B[j,n]
__global__ __launch_bounds__(256) void cb_kernel(const float* __restrict__ xbc,
                                                 float* __restrict__ CB)
{
  const int bc = blockIdx.x;
  __shared__ float Bs[128][32], Cs[128][32];
  float acc[8][8] = {};
  const int ti = threadIdx.x >> 4, tj = threadIdx.x & 15;
  for (int n0 = 0; n0 < 128; n0 += 32) {
    __syncthreads();
    for (int e = threadIdx.x; e < 4096; e += 256) {
      int r = e >> 5, c = e & 31;
      const float* row = xbc + (size_t)(bc * 128 + r) * CONVDIM + DIN;
      Bs[r][c] = row[n0 + c];
      Cs[r][c] = row[DSTATE + n0 + c];
    }
    __syncthreads();
    for (int n = 0; n < 32; ++n) {
      float cv[8], bv[8];
#pragma unroll
      for (int ii = 0; ii < 8; ++ii) cv[ii] = Cs[ti * 8 + ii][n];
#pragma unroll
      for (int jj = 0; jj < 8; ++jj) bv[jj] = Bs[tj * 8 + jj][n];
#pragma unroll
      for (int ii = 0; ii < 8; ++ii)
#pragma unroll
        for (int jj = 0; jj < 8; ++jj) acc[ii][jj] += cv[ii] * bv[jj];
    }
  }
  for (int ii = 0; ii < 8; ++ii)
    for (int jj = 0; jj < 8; ++jj)
      CB[(size_t)bc * 16384 + (size_t)(ti * 8 + ii) * 128 + (tj * 8 + jj)] = acc[ii][jj];
}

// y_intra[i][p] = sum_{j<=i} CB[i][j]*exp(ca_i-ca_j)*dt_j*x[j][p]
__global__ __launch_bounds__(256) void yintra(const float* __restrict__ xbc,
                                              const float* __restrict__ dt,
                                              const float* __restrict__ ca,
                                              const float* __restrict__ CB,
                                              float* __restrict__ ybuf)
{
  const int bc = blockIdx.x >> 5, h = blockIdx.x & 31;
  __shared__ float xdt[128][64];
  __shared__ float cas[128];
  const int tid = threadIdx.x;
  if (tid < 128) cas[tid] = ca[(size_t)blockIdx.x * 128 + tid];
  for (int e = tid * 4; e < 8192; e += 1024) {
    int j = e >> 6, p = e & 63;
    f32x4 xv = *(const f32x4*)(xbc + (size_t)(bc * 128 + j) * CONVDIM + h * 64 + p);
    float dj = dt[(size_t)(bc * 128 + j) * 32 + h];
    xv *= dj;
    *(f32x4*)&xdt[j][p] = xv;
  }
  __syncthreads();
  const int i = tid >> 1, pb = (tid & 1) * 32;
  const float cai = cas[i];
  const float* cbrow = CB + (size_t)bc * 16384 + (size_t)i * 128;
  f32x4 acc[8] = {};
  for (int j = 0; j <= i; ++j) {
    float coeff = cbrow[j] * expf(cai - cas[j]);
    const f32x4* xr = (const f32x4*)&xdt[j][pb];
#pragma unroll
    for (int q = 0; q < 8; ++q) acc[q] += coeff * xr[q];
  }
  float* yo = ybuf + (size_t)(bc * 128 + i) * DIN + h * 64 + pb;
#pragma unroll
  for (int q = 0; q < 8; ++q) *(f32x4*)(yo + q * 4) = acc[q];
}

// states[n][p] = sum_j exp(ca_last-ca_j)*dt_j*B[j][n]*x[j][p]   (layout [bc][h][n][p])
__global__ __launch_bounds__(256) void states_k(const float* __restrict__ xbc,
                                                const float* __restrict__ dt,
                                                const float* __restrict__ ca,
                                                float* __restrict__ states)
{
  const int bc = blockIdx.x >> 5, h = blockIdx.x & 31;
  __shared__ float xw[128][64];
  __shared__ float Bs[32][128];
  __shared__ float warr[128];
  const int tid = threadIdx.x;
  if (tid < 128) {
    float cv = ca[(size_t)blockIdx.x * 128 + tid];
    float clast = ca[(size_t)blockIdx.x * 128 + 127];
    warr[tid] = expf(clast - cv) * dt[(size_t)(bc * 128 + tid) * 32 + h];
  }
  __syncthreads();
  for (int e = tid * 4; e < 8192; e += 1024) {
    int j = e >> 6, p = e & 63;
    f32x4 xv = *(const f32x4*)(xbc + (size_t)(bc * 128 + j) * CONVDIM + h * 64 + p);
    *(f32x4*)&xw[j][p] = xv * warr[j];
  }
  const int w = tid >> 6, p = tid & 63;
  f32x4 acc[8] = {};
  for (int jc = 0; jc < 128; jc += 32) {
    __syncthreads();
    for (int e = tid * 4; e < 4096; e += 1024) {
      int j = e >> 7, n = e & 127;
      *(f32x4*)&Bs[j][n] =
          *(const f32x4*)(xbc + (size_t)(bc * 128 + jc + j) * CONVDIM + DIN + n);
    }
    __syncthreads();
    for (int j = 0; j < 32; ++j) {
      float xv = xw[jc + j][p];
      const f32x4* br = (const f32x4*)&Bs[j][w * 32];
#pragma unroll
      for (int q = 0; q < 8; ++q) acc[q] += xv * br[q];
    }
  }
  float* sb = states + (size_t)blockIdx.x * 8192;
#pragma unroll
  for (int q = 0; q < 8; ++q)
#pragma unroll
    for (int c = 0; c < 4; ++c) {
      int n = w * 32 + q * 4 + c;
      sb[(size_t)n * 64 + p] = acc[q][c];
    }
}

// inter-chunk scan: states[bc] := s_prev ; s = s*cd + states
__global__ __launch_bounds__(256) void scan_k(const float* __restrict__ ca,
                                              float* __restrict__ states)
{
  const int b = blockIdx.x >> 10, h = (blockIdx.x >> 5) & 31, seg = blockIdx.x & 31;
  const int e = seg * 256 + threadIdx.x;
  float s = 0.f;
  for (int c = 0; c < CPB; ++c) {
    int bc = b * CPB + c;
    float cd = expf(ca[(size_t)(bc * 32 + h) * 128 + 127]);
    size_t idx = (size_t)(bc * 32 + h) * 8192 + e;
    float v = states[idx];
    states[idx] = s;
    s = s * cd + v;
  }
}

// y += exp(ca_i)*C[i,:]·s_prev[:, p] + D_h * x
__global__ __launch_bounds__(256) void yinter(const float* __restrict__ xbc,
                                              const float* __restrict__ ca,
                                              const float* __restrict__ Dvec,
                                              const float* __restrict__ states,
                                              float* __restrict__ ybuf)
{
  const int bc = blockIdx.x >> 5, h = blockIdx.x & 31;
  __shared__ float sp[128 * 64];
  __shared__ float cas[128];
  const int tid = threadIdx.x;
  if (tid < 128) cas[tid] = ca[(size_t)blockIdx.x * 128 + tid];
  const float* sg = states + (size_t)blockIdx.x * 8192;
  for (int e = tid * 4; e < 8192; e += 1024)
    *(f32x4*)&sp[e] = *(const f32x4*)(sg + e);
  __syncthreads();
  const int i = tid >> 1, pb = (tid & 1) * 32;
  const float* crow = xbc + (size_t)(bc * 128 + i) * CONVDIM + DIN + DSTATE;
  f32x4 acc[8] = {};
  for (int n = 0; n < 128; ++n) {
    float cn = crow[n];
    const f32x4* sr = (const f32x4*)&sp[n * 64 + pb];
#pragma unroll
    for (int q = 0; q < 8; ++q) acc[q] += cn * sr[q];
  }
  const float ei = expf(cas[i]);
  const float dh = Dvec[h];
  const int tg = bc * 128 + i;
  float* yo = ybuf + (size_t)tg * DIN + h * 64 + pb;
  const float* xv = xbc + (size_t)tg * CONVDIM + h * 64 + pb;
#pragma unroll
  for (int q = 0; q < 8; ++q) {
    f32x4 y = *(const f32x4*)(yo + q * 4);
    f32x4 x4 = *(const f32x4*)(xv + q * 4);
    y += ei * acc[q] + dh * x4;
    *(f32x4*)(yo + q * 4) = y;
  }
}

// yg = y*silu(z); rms(2048) * mnorm_w -> split bf16 planes (stride DIN)
__global__ __launch_bounds__(256) void gate_rms(const float* __restrict__ ybuf,
                                                const float* __restrict__ zx,
                                                const float* __restrict__ nw,
                                                short* __restrict__ outh,
                                                short* __restrict__ outl)
{
  const int row = blockIdx.x, tid = threadIdx.x;
  const float* yr = ybuf + (size_t)row * DIN;
  const float* zr = zx + (size_t)row * DPROJ;
  f32x4 y0 = *(const f32x4*)(yr + tid * 4);
  f32x4 y1 = *(const f32x4*)(yr + 1024 + tid * 4);
  f32x4 z0 = *(const f32x4*)(zr + tid * 4);
  f32x4 z1 = *(const f32x4*)(zr + 1024 + tid * 4);
  f32x4 g0, g1;
#pragma unroll
  for (int c = 0; c < 4; ++c) {
    g0[c] = y0[c] * (z0[c] / (1.f + expf(-z0[c])));
    g1[c] = y1[c] * (z1[c] / (1.f + expf(-z1[c])));
  }
  float ss = 0.f;
#pragma unroll
  for (int c = 0; c < 4; ++c) ss += g0[c] * g0[c] + g1[c] * g1[c];
  for (int o = 32; o; o >>= 1) ss += __shfl_down(ss, o);
  __shared__ float red[4];
  if ((tid & 63) == 0) red[tid >> 6] = ss;
  __syncthreads();
  ss = red[0] + red[1] + red[2] + red[3];
  const float sc = rsqrtf(ss * (1.f / 2048.f) + 1e-6f);
  f32x4 w0 = *(const f32x4*)(nw + tid * 4);
  f32x4 w1 = *(const f32x4*)(nw + 1024 + tid * 4);
  s16x4 h0, h1, l0, l1;
#pragma unroll
  for (int c = 0; c < 4; ++c) {
    float a0 = g0[c] * sc * w0[c];
    float a1 = g1[c] * sc * w1[c];
    h0[c] = f2b(a0); l0[c] = f2b(a0 - b2f(h0[c]));
    h1[c] = f2b(a1); l1[c] = f2b(a1 - b2f(h1[c]));
  }
  *(s16x4*)(outh + (size_t)row * DIN + tid * 4) = h0;
  *(s16x4*)(outh + (size_t)row * DIN + 1024 + tid * 4) = h1;
  *(s16x4*)(outl + (size_t)row * DIN + tid * 4) = l0;
  *(s16x4*)(outl + (size_t)row * DIN + 1024 + tid * 4) = l1;
}

// ---------------- launcher ----------------
extern "C" void kernel_launch(void* const* d_in, const int* in_sizes, int n_in,
                              void* d_out, int out_size, void* d_ws, size_t ws_size,
                              hipStream_t stream)
{
  (void)in_sizes; (void)n_in; (void)out_size; (void)ws_size;
  const int*   tokens = (const int*)d_in[0];
  const float* emb    = (const float*)d_in[1];
  const float* lmb    = (const float*)d_in[2];
  const float* inw    = (const float*)d_in[3];
  const float* cw     = (const float*)d_in[4];
  const float* cbias  = (const float*)d_in[5];
  const float* dtb    = (const float*)d_in[6];
  const float* alog   = (const float*)d_in[7];
  const float* Dvec   = (const float*)d_in[8];
  const float* nw     = (const float*)d_in[9];
  const float* outw   = (const float*)d_in[10];
  const float* uw     = (const float*)d_in[11];
  const float* vw     = (const float*)d_in[12];
  const float* ow     = (const float*)d_in[13];

  char* ws = (char*)d_ws;
  size_t off = 0;
  auto alloc = [&](size_t bytes) { void* p = ws + off; off += (bytes + 255) & ~(size_t)255; return p; };
  short* emb_b  = (short*)alloc((size_t)VOCAB * DIM * 2);          // 65.5 MB
  short* w_inh  = (short*)alloc((size_t)DPROJ * DIM * 2);          //  9.0 MB
  short* w_inl  = (short*)alloc((size_t)DPROJ * DIM * 2);
  short* w_outh = (short*)alloc((size_t)DIM * DIN * 2);            //  4.2 MB
  short* w_outl = (short*)alloc((size_t)DIM * DIN * 2);
  short* w_uvh  = (short*)alloc((size_t)2 * FFN * DIM * 2);        // 16.8 MB
  short* w_uvl  = (short*)alloc((size_t)2 * FFN * DIM * 2);
  short* w_oh   = (short*)alloc((size_t)DIM * FFN * 2);            //  8.4 MB
  short* w_ol   = (short*)alloc((size_t)DIM * FFN * 2);
  float* xbuf   = (float*)alloc((size_t)NTOK * DIM * 4);
  float* xn     = (float*)alloc((size_t)NTOK * DIM * 4);
  short* xnh    = (short*)alloc((size_t)NTOK * DIM * 2);
  short* xnl    = (short*)alloc((size_t)NTOK * DIM * 2);
  short* xnb    = (short*)alloc((size_t)NTOK * DIM * 2);
  float* dtbuf  = (float*)alloc((size_t)NTOK * NH * 4);
  float* cabuf  = (float*)alloc((size_t)NCHUNK * NH * QLEN * 4);
  float* CBbuf  = (float*)alloc((size_t)NCHUNK * QLEN * QLEN * 4);
  short* abh    = (short*)alloc((size_t)NTOK * FFN * 2);           // 33.6 MB
  short* abl    = (short*)alloc((size_t)NTOK * FFN * 2);           // 33.6 MB

  // big transients live in d_out (fully overwritten by the final GEMM)
  char* ob = (char*)d_out;
  float* states = (float*)(ob);                    // 134,217,728 B
  float* zxb    = (float*)(ob + 134217728);        //  71,827,456 B
  float* xbc    = (float*)(ob + 206045184);        //  37,748,736 B
  float* ybuf   = (float*)(ob + 243793920);        //  33,554,432 B (end 277,348,352)

  cvt_f2b_k<<<4096, 256, 0, stream>>>(emb, emb_b, VOCAB * DIM);
  gather_k<<<NTOK, 256, 0, stream>>>(tokens, emb, xbuf);

  for (int it = 0; it < 2 * NLAYER; ++it) {
    const int li = it >> 1;
    if ((it & 1) == 0) {
      cvt_split_k<<<2048, 256, 0, stream>>>(inw + (size_t)li * DPROJ * DIM, w_inh, w_inl, DPROJ * DIM);
      cvt_split_k<<<1024, 256, 0, stream>>>(outw + (size_t)li * DIM * DIN, w_outh, w_outl, DIM * DIN);
      cvt_split_k<<<2048, 256, 0, stream>>>(uw + (size_t)li * FFN * DIM, w_uvh, w_uvl, FFN * DIM);
      cvt_split_k<<<2048, 256, 0, stream>>>(vw + (size_t)li * FFN * DIM,
                                            w_uvh + (size_t)FFN * DIM, w_uvl + (size_t)FFN * DIM, FFN * DIM);
      cvt_split_k<<<2048, 256, 0, stream>>>(ow + (size_t)li * DIM * FFN, w_oh, w_ol, DIM * FFN);
    }
    // x = rms(x) ; mamba
    rms1024<<<NTOK, 256, 0, stream>>>(xbuf, xn, xnh, xnl);
    gemm_bt_split<128><<<dim3((DPROJ + 127) / 128, NTOK / 128), 256, 0, stream>>>(
        xnh, xnl, w_inh, w_inl, zxb, nullptr, DPROJ, DIM, DPROJ);
    conv_silu<<<NTOK, 256, 0, stream>>>(zxb, cw + (size_t)li * CONVDIM * DCONV,
                                        cbias + (size_t)li * CONVDIM, xbc);
    dt_ca<<<NCHUNK * NH, 128, 0, stream>>>(zxb, dtb + li * NH, alog + li * NH, dtbuf, cabuf);
    cb_kernel<<<NCHUNK, 256, 0, stream>>>(xbc, CBbuf);
    yintra<<<NCHUNK * NH, 256, 0, stream>>>(xbc, dtbuf, cabuf, CBbuf, ybuf);
    states_k<<<NCHUNK * NH, 256, 0, stream>>>(xbc, dtbuf, cabuf, states);
    scan_k<<<2048, 256, 0, stream>>>(cabuf, states);
    yinter<<<NCHUNK * NH, 256, 0, stream>>>(xbc, cabuf, Dvec + li * NH, states, ybuf);
    gate_rms<<<NTOK, 256, 0, stream>>>(ybuf, zxb, nw + (size_t)li * DIN, abh, abl);
    gemm_bt_split<64><<<dim3(DIM / 64, NTOK / 128), 256, 0, stream>>>(
        abh, abl, w_outh, w_outl, xbuf, xn, DIM, DIN, DIM);
    // x = rms(x) ; gated FFN
    rms1024<<<NTOK, 256, 0, stream>>>(xbuf, xn, xnh, xnl);
    gemm_uv_split<<<dim3(FFN / 128, NTOK / 128), 256, 0, stream>>>(
        xnh, xnl, w_uvh, w_uvl, abh, abl);
    gemm_bt_split<64><<<dim3(DIM / 64, NTOK / 128), 256, 0, stream>>>(
        abh, abl, w_oh, w_ol, xbuf, xn, DIM, FFN, DIM);
  }

  // lm head (single bf16 is plenty accurate here)
  cvt_f2b_k<<<4096, 256, 0, stream>>>(xbuf, xnb, NTOK * DIM);
  gemm_bt<<<dim3(VOCAB / 128, NTOK / 128), 256, 0, stream>>>(
      xnb, emb_b, (float*)d_out, lmb, VOCAB, DIM, VOCAB);
}

// Round 4
// 7383.337 us; speedup vs baseline: 1.2653x; 1.0537x over previous
//
#include <hip/hip_runtime.h>
#include <hip/hip_bf16.h>

// ---------------- problem constants ----------------
#define BSZ 2
#define LSEQ 2048
#define DIM 1024
#define VOCAB 32000
#define NLAYER 4
#define DSTATE 128
#define DCONV 4
#define HEADDIM 64
#define DIN 2048
#define NH 32
#define CONVDIM 2304          // DIN + 2*DSTATE
#define DPROJ 4384            // 2*DIN + 2*DSTATE + NH
#define FFN 4096
#define QLEN 128
#define NTOK 4096             // BSZ*LSEQ
#define NCHUNK 32             // NTOK/QLEN
#define CPB 16                // chunks per batch

using f32x4 = __attribute__((ext_vector_type(4))) float;
using f16   = _Float16;
using f16x4 = __attribute__((ext_vector_type(4))) _Float16;
using f16x8 = __attribute__((ext_vector_type(8))) _Float16;

__device__ __forceinline__ void gld16(const void* g, void* l) {
  __builtin_amdgcn_global_load_lds(
      (const __attribute__((address_space(1))) unsigned int*)g,
      (__attribute__((address_space(3))) unsigned int*)l, 16, 0, 0);
}

// Tile swizzle: XCD-contiguous + column-chunked (8 bx per chunk, sweep all by)
__device__ __forceinline__ void swz_tiles(int& bx, int& by) {
  const int nx = gridDim.x, ny = gridDim.y;
  const int nwg = nx * ny;
  int bid = blockIdx.y * nx + blockIdx.x;
  if ((nwg & 7) == 0) bid = (bid & 7) * (nwg >> 3) + (bid >> 3);
  const int CW = 8;
  const int nchx = nx / CW;
  const int per = CW * ny;
  const int ch = bid / per;
  if (ch < nchx) {
    int wi = bid - ch * per;
    bx = ch * CW + (wi & (CW - 1));
    by = wi / CW;
  } else {
    int tb = bid - nchx * per;
    int tw = nx - nchx * CW;
    bx = nchx * CW + (tb % tw);
    by = tb / tw;
  }
}

// ---------------- single-fp16 GEMM (lm-head): C = A * B^T + bias ----------------
// Swapped-operand MFMA: lane holds 4 consecutive cols -> dwordx4 stores.
__global__ __launch_bounds__(256) void gemm_bt(
    const f16* __restrict__ A, const f16* __restrict__ B,
    float* __restrict__ Cf, const float* __restrict__ bias,
    int N, int K, int ldc)
{
  __shared__ f16 lA[4096];
  __shared__ f16 lB[4096];
  const int tid  = threadIdx.x;
  const int lane = tid & 63;
  const int wid  = tid >> 6;
  int bx, by; swz_tiles(bx, by);
  const int m0 = by * 128;
  const int n0 = bx * 128;

  const int r0 = tid >> 2;
  const int kc = (tid & 3) << 3;
  const f16* ga0 = A + (size_t)(m0 + r0) * K + kc;
  const f16* ga1 = ga0 + (size_t)64 * K;
  const f16* gb0 = B + (size_t)(n0 + r0) * K + kc;
  const f16* gb1 = B + (size_t)(n0 + 64 + r0) * K + kc;

  const int fr = lane & 15;
  const int fk = (lane >> 4) << 3;
  const int wm = (wid >> 1) << 6;
  const int wn = (wid & 1) << 6;

  f32x4 acc[4][4] = {};   // [fi = col-frag][fj = row-frag]

  for (int kk = 0; kk < K; kk += 32) {
    gld16(ga0 + kk, &lA[tid * 8]);
    gld16(ga1 + kk, &lA[2048 + tid * 8]);
    gld16(gb0 + kk, &lB[tid * 8]);
    gld16(gb1 + kk, &lB[2048 + tid * 8]);
    __syncthreads();
    f16x8 af[4], bf[4];
#pragma unroll
    for (int j = 0; j < 4; ++j)
      af[j] = *(const f16x8*)&lA[(wm + j * 16 + fr) * 32 + fk];
#pragma unroll
    for (int i = 0; i < 4; ++i)
      bf[i] = *(const f16x8*)&lB[(wn + i * 16 + fr) * 32 + fk];
#pragma unroll
    for (int i = 0; i < 4; ++i)
#pragma unroll
      for (int j = 0; j < 4; ++j)
        acc[i][j] = __builtin_amdgcn_mfma_f32_16x16x32_f16(bf[i], af[j], acc[i][j], 0, 0, 0);
    __syncthreads();
  }

  const int c4 = (lane >> 4) << 2;   // col offset
  const int rr = lane & 15;          // row offset
#pragma unroll
  for (int i = 0; i < 4; ++i) {
    const int col = n0 + wn + i * 16 + c4;
    f32x4 bv = bias ? *(const f32x4*)(bias + col) : f32x4{0, 0, 0, 0};
#pragma unroll
    for (int j = 0; j < 4; ++j) {
      const int row = m0 + wm + j * 16 + rr;
      *(f32x4*)(Cf + (size_t)row * ldc + col) = acc[i][j] + bv;
    }
  }
}

// ---------------- fp16 2-term split GEMM: C = (Ah+Al) * B^T (+res) ----------------
template <int BN>
__global__ __launch_bounds__(256) void gemm_sp(
    const f16* __restrict__ Ah, const f16* __restrict__ Al,
    const f16* __restrict__ B,
    float* __restrict__ Cf, const float* __restrict__ res,
    int N, int K, int ldc)
{
  constexpr int JN = BN / 32;
  __shared__ f16 lAh[4096], lAl[4096];
  __shared__ f16 lB[BN * 32];
  const int tid  = threadIdx.x;
  const int lane = tid & 63;
  const int wid  = tid >> 6;
  int bx, by; swz_tiles(bx, by);
  const int m0 = by * 128;
  const int n0 = bx * BN;

  const int r0 = tid >> 2;
  const int kc = (tid & 3) << 3;
  const size_t aoff0 = (size_t)(m0 + r0) * K + kc;
  const size_t aoff1 = aoff0 + (size_t)64 * K;
  int nr0 = n0 + r0;      if (nr0 > N - 1) nr0 = N - 1;
  const size_t boff0 = (size_t)nr0 * K + kc;
  size_t boff1 = 0;
  if constexpr (BN == 128) {
    int nr1 = n0 + 64 + r0; if (nr1 > N - 1) nr1 = N - 1;
    boff1 = (size_t)nr1 * K + kc;
  }

  const int fr = lane & 15;
  const int fk = (lane >> 4) << 3;
  const int wm = (wid >> 1) << 6;
  const int wn = (wid & 1) * (BN / 2);

  f32x4 acc[JN][4] = {};   // [fi col][fj row]

  for (int kk = 0; kk < K; kk += 32) {
    gld16(Ah + aoff0 + kk, &lAh[tid * 8]);
    gld16(Ah + aoff1 + kk, &lAh[2048 + tid * 8]);
    gld16(Al + aoff0 + kk, &lAl[tid * 8]);
    gld16(Al + aoff1 + kk, &lAl[2048 + tid * 8]);
    gld16(B + boff0 + kk, &lB[tid * 8]);
    if constexpr (BN == 128)
      gld16(B + boff1 + kk, &lB[2048 + tid * 8]);
    __syncthreads();
    f16x8 ah[4], al[4], bf[JN];
#pragma unroll
    for (int j = 0; j < 4; ++j) {
      ah[j] = *(const f16x8*)&lAh[(wm + j * 16 + fr) * 32 + fk];
      al[j] = *(const f16x8*)&lAl[(wm + j * 16 + fr) * 32 + fk];
    }
#pragma unroll
    for (int i = 0; i < JN; ++i)
      bf[i] = *(const f16x8*)&lB[(wn + i * 16 + fr) * 32 + fk];
#pragma unroll
    for (int i = 0; i < JN; ++i)
#pragma unroll
      for (int j = 0; j < 4; ++j) {
        acc[i][j] = __builtin_amdgcn_mfma_f32_16x16x32_f16(bf[i], ah[j], acc[i][j], 0, 0, 0);
        acc[i][j] = __builtin_amdgcn_mfma_f32_16x16x32_f16(bf[i], al[j], acc[i][j], 0, 0, 0);
      }
    __syncthreads();
  }

  const int c4 = (lane >> 4) << 2;
  const int rr = lane & 15;
#pragma unroll
  for (int i = 0; i < JN; ++i) {
    const int col = n0 + wn + i * 16 + c4;
    if (col >= N) continue;            // col,N multiples of 4 -> x4 safe
#pragma unroll
    for (int j = 0; j < 4; ++j) {
      const int row = m0 + wm + j * 16 + rr;
      size_t off = (size_t)row * ldc + col;
      f32x4 v = acc[i][j];
      if (res) v += *(const f32x4*)(res + off);
      *(f32x4*)(Cf + off) = v;
    }
  }
}

// ---------------- fused UV GEMM: G = splitf16((A U^T) .* (A V^T)) ----------------
__global__ __launch_bounds__(256) void gemm_uv(
    const f16* __restrict__ Ah, const f16* __restrict__ Al,
    const f16* __restrict__ B,
    f16* __restrict__ Gh, f16* __restrict__ Gl)
{
  __shared__ f16 lAh[4096], lAl[4096], lB[4096];
  const int tid  = threadIdx.x;
  const int lane = tid & 63;
  const int wid  = tid >> 6;
  int bx, by; swz_tiles(bx, by);
  const int m0 = by * 128;
  const int n0 = bx * 128;
  const int K = DIM;

  const int r0 = tid >> 2;
  const int kc = (tid & 3) << 3;
  const size_t aoff0 = (size_t)(m0 + r0) * K + kc;
  const size_t aoff1 = aoff0 + (size_t)64 * K;

  const int fr = lane & 15;
  const int fk = (lane >> 4) << 3;
  const int wm = (wid >> 1) << 6;
  const int wn = (wid & 1) << 6;

  f32x4 accu[4][4] = {}, accv[4][4] = {};

  auto half_loop = [&](size_t b0, size_t b1, f32x4 (&acc)[4][4]) {
    for (int kk = 0; kk < K; kk += 32) {
      gld16(Ah + aoff0 + kk, &lAh[tid * 8]);
      gld16(Ah + aoff1 + kk, &lAh[2048 + tid * 8]);
      gld16(Al + aoff0 + kk, &lAl[tid * 8]);
      gld16(Al + aoff1 + kk, &lAl[2048 + tid * 8]);
      gld16(B + b0 + kk, &lB[tid * 8]);
      gld16(B + b1 + kk, &lB[2048 + tid * 8]);
      __syncthreads();
      f16x8 ah[4], al[4], bf[4];
#pragma unroll
      for (int j = 0; j < 4; ++j) {
        ah[j] = *(const f16x8*)&lAh[(wm + j * 16 + fr) * 32 + fk];
        al[j] = *(const f16x8*)&lAl[(wm + j * 16 + fr) * 32 + fk];
      }
#pragma unroll
      for (int i = 0; i < 4; ++i)
        bf[i] = *(const f16x8*)&lB[(wn + i * 16 + fr) * 32 + fk];
#pragma unroll
      for (int i = 0; i < 4; ++i)
#pragma unroll
        for (int j = 0; j < 4; ++j) {
          acc[i][j] = __builtin_amdgcn_mfma_f32_16x16x32_f16(bf[i], ah[j], acc[i][j], 0, 0, 0);
          acc[i][j] = __builtin_amdgcn_mfma_f32_16x16x32_f16(bf[i], al[j], acc[i][j], 0, 0, 0);
        }
      __syncthreads();
    }
  };

  const size_t bu0 = (size_t)(n0 + r0) * K + kc;
  const size_t bu1 = bu0 + (size_t)64 * K;
  const size_t bv0 = (size_t)(FFN + n0 + r0) * K + kc;
  const size_t bv1 = bv0 + (size_t)64 * K;
  half_loop(bu0, bu1, accu);
  half_loop(bv0, bv1, accv);

  const int c4 = (lane >> 4) << 2;
  const int rr = lane & 15;
#pragma unroll
  for (int i = 0; i < 4; ++i) {
    const int col = n0 + wn + i * 16 + c4;
#pragma unroll
    for (int j = 0; j < 4; ++j) {
      const int row = m0 + wm + j * 16 + rr;
      size_t off = (size_t)row * FFN + col;
      f16x4 h, l;
#pragma unroll
      for (int r = 0; r < 4; ++r) {
        float g = accu[i][j][r] * accv[i][j][r];
        f16 hh = (f16)g;
        h[r] = hh;
        l[r] = (f16)(g - (float)hh);
      }
      *(f16x4*)(Gh + off) = h;
      *(f16x4*)(Gl + off) = l;
    }
  }
}

// ---------------- small kernels ----------------
__global__ __launch_bounds__(256) void cvt_f2h_k(const float* __restrict__ src,
                                                 f16* __restrict__ dst, int n)
{
  for (size_t i = ((size_t)blockIdx.x * 256 + threadIdx.x) * 4; i < (size_t)n;
       i += (size_t)gridDim.x * 1024) {
    f32x4 v = *(const f32x4*)(src + i);
    f16x4 o;
#pragma unroll
    for (int c = 0; c < 4; ++c) o[c] = (f16)v[c];
    *(f16x4*)(dst + i) = o;
  }
}

__global__ __launch_bounds__(256) void gather_k(const int* __restrict__ tok,
                                                const float* __restrict__ emb,
                                                float* __restrict__ x)
{
  const int row = blockIdx.x;
  const int t = tok[row];
  const f32x4* s = (const f32x4*)(emb + (size_t)t * DIM);
  f32x4* d = (f32x4*)(x + (size_t)row * DIM);
  d[threadIdx.x] = s[threadIdx.x];
}

// rms over 1024; writes f32 and fp16 hi/lo planes
__global__ __launch_bounds__(256) void rms1024(const float* __restrict__ in,
                                               float* __restrict__ outf,
                                               f16* __restrict__ outh,
                                               f16* __restrict__ outl)
{
  const int row = blockIdx.x, tid = threadIdx.x;
  f32x4 v = ((const f32x4*)(in + (size_t)row * DIM))[tid];
  float ss = v[0] * v[0] + v[1] * v[1] + v[2] * v[2] + v[3] * v[3];
  for (int o = 32; o; o >>= 1) ss += __shfl_down(ss, o);
  __shared__ float red[4];
  if ((tid & 63) == 0) red[tid >> 6] = ss;
  __syncthreads();
  ss = red[0] + red[1] + red[2] + red[3];
  const float sc = rsqrtf(ss * (1.f / 1024.f) + 1e-6f);
  f32x4 o4 = v * sc;
  ((f32x4*)(outf + (size_t)row * DIM))[tid] = o4;
  f16x4 h, l;
#pragma unroll
  for (int c = 0; c < 4; ++c) {
    h[c] = (f16)o4[c];
    l[c] = (f16)(o4[c] - (float)h[c]);
  }
  ((f16x4*)(outh + (size_t)row * DIM))[tid] = h;
  ((f16x4*)(outl + (size_t)row * DIM))[tid] = l;
}

// causal depthwise conv (width 4) + bias + silu on xBC slice of zxbcdt
__global__ __launch_bounds__(256) void conv_silu(const float* __restrict__ zx,
                                                 const float* __restrict__ cw,
                                                 const float* __restrict__ cbias,
                                                 float* __restrict__ xbc)
{
  const int t = blockIdx.x;
  const int l = t & (LSEQ - 1);
  for (int c0 = threadIdx.x * 4; c0 < CONVDIM; c0 += 1024) {
    float w[4][4], a[4];
#pragma unroll
    for (int cc = 0; cc < 4; ++cc) {
      f32x4 wv = *(const f32x4*)(cw + (size_t)(c0 + cc) * 4);
      w[cc][0] = wv[0]; w[cc][1] = wv[1]; w[cc][2] = wv[2]; w[cc][3] = wv[3];
      a[cc] = cbias[c0 + cc];
    }
#pragma unroll
    for (int j = 0; j < 4; ++j) {
      int pos = l - 3 + j;
      if (pos < 0) continue;
      f32x4 xv = *(const f32x4*)(zx + (size_t)(t - 3 + j) * DPROJ + DIN + c0);
      a[0] += xv[0] * w[0][j]; a[1] += xv[1] * w[1][j];
      a[2] += xv[2] * w[2][j]; a[3] += xv[3] * w[3][j];
    }
    f32x4 o;
#pragma unroll
    for (int cc = 0; cc < 4; ++cc) o[cc] = a[cc] / (1.f + expf(-a[cc]));
    *(f32x4*)(xbc + (size_t)t * CONVDIM + c0) = o;
  }
}

// dt = softplus(dtraw + bias); a = dt * (-exp(A_log)); ca = cumsum within chunk
__global__ __launch_bounds__(128) void dt_ca(const float* __restrict__ zx,
                                             const float* __restrict__ dtb,
                                             const float* __restrict__ alog,
                                             float* __restrict__ dt,
                                             float* __restrict__ ca)
{
  const int bc = blockIdx.x >> 5, h = blockIdx.x & 31, q = threadIdx.x;
  const int t = bc * 128 + q;
  float raw = zx[(size_t)t * DPROJ + (DIN + CONVDIM) + h] + dtb[h];
  float d = raw > 20.f ? raw : log1pf(expf(raw));
  dt[t * 32 + h] = d;
  float a = -expf(alog[h]) * d;
  __shared__ float s[128];
  s[q] = a;
  __syncthreads();
  for (int off = 1; off < 128; off <<= 1) {
    float v = (q >= off) ? s[q - off] : 0.f;
    __syncthreads();
    s[q] += v;
    __syncthreads();
  }
  ca[(size_t)blockIdx.x * 128 + q] = s[q];
}

// CB[bc][i][j] = sum_n C[i,n]*B[j,n]
__global__ __launch_bounds__(256) void cb_kernel(const float* __restrict__ xbc,
                                                 float* __restrict__ CB)
{
  const int bc = blockIdx.x;
  __shared__ float Bs[128][32], Cs[128][32];
  float acc[8][8] = {};
  const int ti = threadIdx.x >> 4, tj = threadIdx.x & 15;
  for (int n0 = 0; n0 < 128; n0 += 32) {
    __syncthreads();
    for (int e = threadIdx.x; e < 4096; e += 256) {
      int r = e >> 5, c = e & 31;
      const float* row = xbc + (size_t)(bc * 128 + r) * CONVDIM + DIN;
      Bs[r][c] = row[n0 + c];
      Cs[r][c] = row[DSTATE + n0 + c];
    }
    __syncthreads();
    for (int n = 0; n < 32; ++n) {
      float cv[8], bv[8];
#pragma unroll
      for (int ii = 0; ii < 8; ++ii) cv[ii] = Cs[ti * 8 + ii][n];
#pragma unroll
      for (int jj = 0; jj < 8; ++jj) bv[jj] = Bs[tj * 8 + jj][n];
#pragma unroll
      for (int ii = 0; ii < 8; ++ii)
#pragma unroll
        for (int jj = 0; jj < 8; ++jj) acc[ii][jj] += cv[ii] * bv[jj];
    }
  }
  for (int ii = 0; ii < 8; ++ii)
    for (int jj = 0; jj < 8; ++jj)
      CB[(size_t)bc * 16384 + (size_t)(ti * 8 + ii) * 128 + (tj * 8 + jj)] = acc[ii][jj];
}

// y_intra[i][p] = sum_{j<=i} CB[i][j]*exp(ca_i-ca_j)*dt_j*x[j][p]
__global__ __launch_bounds__(256) void yintra(const float* __restrict__ xbc,
                                              const float* __restrict__ dt,
                                              const float* __restrict__ ca,
                                              const float* __restrict__ CB,
                                              float* __restrict__ ybuf)
{
  const int bc = blockIdx.x >> 5, h = blockIdx.x & 31;
  __shared__ float xdt[128][64];
  __shared__ float cas[128];
  const int tid = threadIdx.x;
  if (tid < 128) cas[tid] = ca[(size_t)blockIdx.x * 128 + tid];
  for (int e = tid * 4; e < 8192; e += 1024) {
    int j = e >> 6, p = e & 63;
    f32x4 xv = *(const f32x4*)(xbc + (size_t)(bc * 128 + j) * CONVDIM + h * 64 + p);
    float dj = dt[(size_t)(bc * 128 + j) * 32 + h];
    xv *= dj;
    *(f32x4*)&xdt[j][p] = xv;
  }
  __syncthreads();
  const int i = tid >> 1, pb = (tid & 1) * 32;
  const float cai = cas[i];
  const float* cbrow = CB + (size_t)bc * 16384 + (size_t)i * 128;
  f32x4 acc[8] = {};
  for (int j = 0; j <= i; ++j) {
    float coeff = cbrow[j] * expf(cai - cas[j]);
    const f32x4* xr = (const f32x4*)&xdt[j][pb];
#pragma unroll
    for (int q = 0; q < 8; ++q) acc[q] += coeff * xr[q];
  }
  float* yo = ybuf + (size_t)(bc * 128 + i) * DIN + h * 64 + pb;
#pragma unroll
  for (int q = 0; q < 8; ++q) *(f32x4*)(yo + q * 4) = acc[q];
}

// states[n][p] = sum_j exp(ca_last-ca_j)*dt_j*B[j][n]*x[j][p]   (layout [bc][h][n][p])
__global__ __launch_bounds__(256) void states_k(const float* __restrict__ xbc,
                                                const float* __restrict__ dt,
                                                const float* __restrict__ ca,
                                                float* __restrict__ states)
{
  const int bc = blockIdx.x >> 5, h = blockIdx.x & 31;
  __shared__ float xw[128][64];
  __shared__ float Bs[32][128];
  __shared__ float warr[128];
  const int tid = threadIdx.x;
  if (tid < 128) {
    float cv = ca[(size_t)blockIdx.x * 128 + tid];
    float clast = ca[(size_t)blockIdx.x * 128 + 127];
    warr[tid] = expf(clast - cv) * dt[(size_t)(bc * 128 + tid) * 32 + h];
  }
  __syncthreads();
  for (int e = tid * 4; e < 8192; e += 1024) {
    int j = e >> 6, p = e & 63;
    f32x4 xv = *(const f32x4*)(xbc + (size_t)(bc * 128 + j) * CONVDIM + h * 64 + p);
    *(f32x4*)&xw[j][p] = xv * warr[j];
  }
  const int w = tid >> 6, p = tid & 63;
  f32x4 acc[8] = {};
  for (int jc = 0; jc < 128; jc += 32) {
    __syncthreads();
    for (int e = tid * 4; e < 4096; e += 1024) {
      int j = e >> 7, n = e & 127;
      *(f32x4*)&Bs[j][n] =
          *(const f32x4*)(xbc + (size_t)(bc * 128 + jc + j) * CONVDIM + DIN + n);
    }
    __syncthreads();
    for (int j = 0; j < 32; ++j) {
      float xv = xw[jc + j][p];
      const f32x4* br = (const f32x4*)&Bs[j][w * 32];
#pragma unroll
      for (int q = 0; q < 8; ++q) acc[q] += xv * br[q];
    }
  }
  float* sb = states + (size_t)blockIdx.x * 8192;
#pragma unroll
  for (int q = 0; q < 8; ++q)
#pragma unroll
    for (int c = 0; c < 4; ++c) {
      int n = w * 32 + q * 4 + c;
      sb[(size_t)n * 64 + p] = acc[q][c];
    }
}

// inter-chunk scan: states[bc] := s_prev ; s = s*cd + states
__global__ __launch_bounds__(256) void scan_k(const float* __restrict__ ca,
                                              float* __restrict__ states)
{
  const int b = blockIdx.x >> 10, h = (blockIdx.x >> 5) & 31, seg = blockIdx.x & 31;
  const int e = seg * 256 + threadIdx.x;
  float s = 0.f;
  for (int c = 0; c < CPB; ++c) {
    int bc = b * CPB + c;
    float cd = expf(ca[(size_t)(bc * 32 + h) * 128 + 127]);
    size_t idx = (size_t)(bc * 32 + h) * 8192 + e;
    float v = states[idx];
    states[idx] = s;
    s = s * cd + v;
  }
}

// y += exp(ca_i)*C[i,:]·s_prev[:, p] + D_h * x
__global__ __launch_bounds__(256) void yinter(const float* __restrict__ xbc,
                                              const float* __restrict__ ca,
                                              const float* __restrict__ Dvec,
                                              const float* __restrict__ states,
                                              float* __restrict__ ybuf)
{
  const int bc = blockIdx.x >> 5, h = blockIdx.x & 31;
  __shared__ float sp[128 * 64];
  __shared__ float cas[128];
  const int tid = threadIdx.x;
  if (tid < 128) cas[tid] = ca[(size_t)blockIdx.x * 128 + tid];
  const float* sg = states + (size_t)blockIdx.x * 8192;
  for (int e = tid * 4; e < 8192; e += 1024)
    *(f32x4*)&sp[e] = *(const f32x4*)(sg + e);
  __syncthreads();
  const int i = tid >> 1, pb = (tid & 1) * 32;
  const float* crow = xbc + (size_t)(bc * 128 + i) * CONVDIM + DIN + DSTATE;
  f32x4 acc[8] = {};
  for (int n = 0; n < 128; ++n) {
    float cn = crow[n];
    const f32x4* sr = (const f32x4*)&sp[n * 64 + pb];
#pragma unroll
    for (int q = 0; q < 8; ++q) acc[q] += cn * sr[q];
  }
  const float ei = expf(cas[i]);
  const float dh = Dvec[h];
  const int tg = bc * 128 + i;
  float* yo = ybuf + (size_t)tg * DIN + h * 64 + pb;
  const float* xv = xbc + (size_t)tg * CONVDIM + h * 64 + pb;
#pragma unroll
  for (int q = 0; q < 8; ++q) {
    f32x4 y = *(const f32x4*)(yo + q * 4);
    f32x4 x4 = *(const f32x4*)(xv + q * 4);
    y += ei * acc[q] + dh * x4;
    *(f32x4*)(yo + q * 4) = y;
  }
}

// yg = y*silu(z); rms(2048) * mnorm_w -> fp16 hi/lo planes (stride DIN)
__global__ __launch_bounds__(256) void gate_rms(const float* __restrict__ ybuf,
                                                const float* __restrict__ zx,
                                                const float* __restrict__ nw,
                                                f16* __restrict__ outh,
                                                f16* __restrict__ outl)
{
  const int row = blockIdx.x, tid = threadIdx.x;
  const float* yr = ybuf + (size_t)row * DIN;
  const float* zr = zx + (size_t)row * DPROJ;
  f32x4 y0 = *(const f32x4*)(yr + tid * 4);
  f32x4 y1 = *(const f32x4*)(yr + 1024 + tid * 4);
  f32x4 z0 = *(const f32x4*)(zr + tid * 4);
  f32x4 z1 = *(const f32x4*)(zr + 1024 + tid * 4);
  f32x4 g0, g1;
#pragma unroll
  for (int c = 0; c < 4; ++c) {
    g0[c] = y0[c] * (z0[c] / (1.f + expf(-z0[c])));
    g1[c] = y1[c] * (z1[c] / (1.f + expf(-z1[c])));
  }
  float ss = 0.f;
#pragma unroll
  for (int c = 0; c < 4; ++c) ss += g0[c] * g0[c] + g1[c] * g1[c];
  for (int o = 32; o; o >>= 1) ss += __shfl_down(ss, o);
  __shared__ float red[4];
  if ((tid & 63) == 0) red[tid >> 6] = ss;
  __syncthreads();
  ss = red[0] + red[1] + red[2] + red[3];
  const float sc = rsqrtf(ss * (1.f / 2048.f) + 1e-6f);
  f32x4 w0 = *(const f32x4*)(nw + tid * 4);
  f32x4 w1 = *(const f32x4*)(nw + 1024 + tid * 4);
  f16x4 h0, h1, l0, l1;
#pragma unroll
  for (int c = 0; c < 4; ++c) {
    float a0 = g0[c] * sc * w0[c];
    float a1 = g1[c] * sc * w1[c];
    h0[c] = (f16)a0; l0[c] = (f16)(a0 - (float)h0[c]);
    h1[c] = (f16)a1; l1[c] = (f16)(a1 - (float)h1[c]);
  }
  *(f16x4*)(outh + (size_t)row * DIN + tid * 4) = h0;
  *(f16x4*)(outh + (size_t)row * DIN + 1024 + tid * 4) = h1;
  *(f16x4*)(outl + (size_t)row * DIN + tid * 4) = l0;
  *(f16x4*)(outl + (size_t)row * DIN + 1024 + tid * 4) = l1;
}

// ---------------- launcher ----------------
extern "C" void kernel_launch(void* const* d_in, const int* in_sizes, int n_in,
                              void* d_out, int out_size, void* d_ws, size_t ws_size,
                              hipStream_t stream)
{
  (void)in_sizes; (void)n_in; (void)out_size; (void)ws_size;
  const int*   tokens = (const int*)d_in[0];
  const float* emb    = (const float*)d_in[1];
  const float* lmb    = (const float*)d_in[2];
  const float* inw    = (const float*)d_in[3];
  const float* cw     = (const float*)d_in[4];
  const float* cbias  = (const float*)d_in[5];
  const float* dtb    = (const float*)d_in[6];
  const float* alog   = (const float*)d_in[7];
  const float* Dvec   = (const float*)d_in[8];
  const float* nw     = (const float*)d_in[9];
  const float* outw   = (const float*)d_in[10];
  const float* uw     = (const float*)d_in[11];
  const float* vw     = (const float*)d_in[12];
  const float* ow     = (const float*)d_in[13];

  char* ws = (char*)d_ws;
  size_t off = 0;
  auto alloc = [&](size_t bytes) { void* p = ws + off; off += (bytes + 255) & ~(size_t)255; return p; };
  f16* emb_h  = (f16*)alloc((size_t)VOCAB * DIM * 2);          // 65.5 MB
  f16* w_in   = (f16*)alloc((size_t)DPROJ * DIM * 2);          //  9.0 MB
  f16* w_out  = (f16*)alloc((size_t)DIM * DIN * 2);            //  4.2 MB
  f16* w_uv   = (f16*)alloc((size_t)2 * FFN * DIM * 2);        // 16.8 MB
  f16* w_o    = (f16*)alloc((size_t)DIM * FFN * 2);            //  8.4 MB
  float* xbuf = (float*)alloc((size_t)NTOK * DIM * 4);
  float* xn   = (float*)alloc((size_t)NTOK * DIM * 4);
  f16* xnh    = (f16*)alloc((size_t)NTOK * DIM * 2);
  f16* xnl    = (f16*)alloc((size_t)NTOK * DIM * 2);
  f16* xh_lm  = (f16*)alloc((size_t)NTOK * DIM * 2);
  float* dtbuf = (float*)alloc((size_t)NTOK * NH * 4);
  float* cabuf = (float*)alloc((size_t)NCHUNK * NH * QLEN * 4);
  float* CBbuf = (float*)alloc((size_t)NCHUNK * QLEN * QLEN * 4);
  f16* abh    = (f16*)alloc((size_t)NTOK * FFN * 2);           // 33.6 MB
  f16* abl    = (f16*)alloc((size_t)NTOK * FFN * 2);           // 33.6 MB

  // big transients live in d_out (fully overwritten by the final GEMM)
  char* ob = (char*)d_out;
  float* states = (float*)(ob);                    // 134,217,728 B
  float* zxb    = (float*)(ob + 134217728);        //  71,827,456 B
  float* xbc    = (float*)(ob + 206045184);        //  37,748,736 B
  float* ybuf   = (float*)(ob + 243793920);        //  33,554,432 B

  cvt_f2h_k<<<4096, 256, 0, stream>>>(emb, emb_h, VOCAB * DIM);
  gather_k<<<NTOK, 256, 0, stream>>>(tokens, emb, xbuf);

  for (int it = 0; it < 2 * NLAYER; ++it) {
    const int li = it >> 1;
    if ((it & 1) == 0) {
      cvt_f2h_k<<<2048, 256, 0, stream>>>(inw + (size_t)li * DPROJ * DIM, w_in, DPROJ * DIM);
      cvt_f2h_k<<<1024, 256, 0, stream>>>(outw + (size_t)li * DIM * DIN, w_out, DIM * DIN);
      cvt_f2h_k<<<2048, 256, 0, stream>>>(uw + (size_t)li * FFN * DIM, w_uv, FFN * DIM);
      cvt_f2h_k<<<2048, 256, 0, stream>>>(vw + (size_t)li * FFN * DIM, w_uv + (size_t)FFN * DIM, FFN * DIM);
      cvt_f2h_k<<<2048, 256, 0, stream>>>(ow + (size_t)li * DIM * FFN, w_o, DIM * FFN);
    }
    // x = rms(x) ; mamba
    rms1024<<<NTOK, 256, 0, stream>>>(xbuf, xn, xnh, xnl);
    gemm_sp<128><<<dim3((DPROJ + 127) / 128, NTOK / 128), 256, 0, stream>>>(
        xnh, xnl, w_in, zxb, nullptr, DPROJ, DIM, DPROJ);
    conv_silu<<<NTOK, 256, 0, stream>>>(zxb, cw + (size_t)li * CONVDIM * DCONV,
                                        cbias + (size_t)li * CONVDIM, xbc);
    dt_ca<<<NCHUNK * NH, 128, 0, stream>>>(zxb, dtb + li * NH, alog + li * NH, dtbuf, cabuf);
    cb_kernel<<<NCHUNK, 256, 0, stream>>>(xbc, CBbuf);
    yintra<<<NCHUNK * NH, 256, 0, stream>>>(xbc, dtbuf, cabuf, CBbuf, ybuf);
    states_k<<<NCHUNK * NH, 256, 0, stream>>>(xbc, dtbuf, cabuf, states);
    scan_k<<<2048, 256, 0, stream>>>(cabuf, states);
    yinter<<<NCHUNK * NH, 256, 0, stream>>>(xbc, cabuf, Dvec + li * NH, states, ybuf);
    gate_rms<<<NTOK, 256, 0, stream>>>(ybuf, zxb, nw + (size_t)li * DIN, abh, abl);
    gemm_sp<64><<<dim3(DIM / 64, NTOK / 128), 256, 0, stream>>>(
        abh, abl, w_out, xbuf, xn, DIM, DIN, DIM);
    // x = rms(x) ; gated FFN
    rms1024<<<NTOK, 256, 0, stream>>>(xbuf, xn, xnh, xnl);
    gemm_uv<<<dim3(FFN / 128, NTOK / 128), 256, 0, stream>>>(
        xnh, xnl, w_uv, abh, abl);
    gemm_sp<64><<<dim3(DIM / 64, NTOK / 128), 256, 0, stream>>>(
        abh, abl, w_o, xbuf, xn, DIM, FFN, DIM);
  }

  // lm head (single fp16)
  cvt_f2h_k<<<4096, 256, 0, stream>>>(xbuf, xh_lm, NTOK * DIM);
  gemm_bt<<<dim3(VOCAB / 128, NTOK / 128), 256, 0, stream>>>(
      xh_lm, emb_h, (float*)d_out, lmb, VOCAB, DIM, VOCAB);
}

// Round 5
// 5508.093 us; speedup vs baseline: 1.6960x; 1.3405x over previous
//
#include <hip/hip_runtime.h>
#include <hip/hip_bf16.h>

// ---------------- problem constants ----------------
#define BSZ 2
#define LSEQ 2048
#define DIM 1024
#define VOCAB 32000
#define NLAYER 4
#define DSTATE 128
#define DCONV 4
#define HEADDIM 64
#define DIN 2048
#define NH 32
#define CONVDIM 2304          // DIN + 2*DSTATE
#define DPROJ 4384            // 2*DIN + 2*DSTATE + NH
#define FFN 4096
#define QLEN 128
#define NTOK 4096             // BSZ*LSEQ
#define NCHUNK 32             // NTOK/QLEN
#define CPB 16                // chunks per batch

using f32x4 = __attribute__((ext_vector_type(4))) float;
using f16   = _Float16;
using f16x4 = __attribute__((ext_vector_type(4))) _Float16;
using f16x8 = __attribute__((ext_vector_type(8))) _Float16;

__device__ __forceinline__ void gld16(const void* g, void* l) {
  __builtin_amdgcn_global_load_lds(
      (const __attribute__((address_space(1))) unsigned int*)g,
      (__attribute__((address_space(3))) unsigned int*)l, 16, 0, 0);
}

// Tile swizzle: XCD-contiguous + column-chunked (8 bx per chunk, sweep all by)
__device__ __forceinline__ void swz_tiles(int& bx, int& by) {
  const int nx = gridDim.x, ny = gridDim.y;
  const int nwg = nx * ny;
  int bid = blockIdx.y * nx + blockIdx.x;
  if ((nwg & 7) == 0) bid = (bid & 7) * (nwg >> 3) + (bid >> 3);
  const int CW = 8;
  const int nchx = nx / CW;
  const int per = CW * ny;
  const int ch = bid / per;
  if (ch < nchx) {
    int wi = bid - ch * per;
    bx = ch * CW + (wi & (CW - 1));
    by = wi / CW;
  } else {
    int tb = bid - nchx * per;
    int tw = nx - nchx * CW;
    bx = nchx * CW + (tb % tw);
    by = tb / tw;
  }
}

// ---------------- fp16 GEMM (lm-head): C = A * B^T + bias ----------------
// Swapped-operand MFMA: lane holds 4 consecutive cols -> dwordx4 stores.
__global__ __launch_bounds__(256) void gemm_bt(
    const f16* __restrict__ A, const f16* __restrict__ B,
    float* __restrict__ Cf, const float* __restrict__ bias,
    int N, int K, int ldc)
{
  __shared__ f16 lA[4096];
  __shared__ f16 lB[4096];
  const int tid  = threadIdx.x;
  const int lane = tid & 63;
  const int wid  = tid >> 6;
  int bx, by; swz_tiles(bx, by);
  const int m0 = by * 128;
  const int n0 = bx * 128;

  const int r0 = tid >> 2;
  const int kc = (tid & 3) << 3;
  const f16* ga0 = A + (size_t)(m0 + r0) * K + kc;
  const f16* ga1 = ga0 + (size_t)64 * K;
  const f16* gb0 = B + (size_t)(n0 + r0) * K + kc;
  const f16* gb1 = B + (size_t)(n0 + 64 + r0) * K + kc;

  const int fr = lane & 15;
  const int fk = (lane >> 4) << 3;
  const int wm = (wid >> 1) << 6;
  const int wn = (wid & 1) << 6;

  f32x4 acc[4][4] = {};   // [fi = col-frag][fj = row-frag]

  for (int kk = 0; kk < K; kk += 32) {
    gld16(ga0 + kk, &lA[tid * 8]);
    gld16(ga1 + kk, &lA[2048 + tid * 8]);
    gld16(gb0 + kk, &lB[tid * 8]);
    gld16(gb1 + kk, &lB[2048 + tid * 8]);
    __syncthreads();
    f16x8 af[4], bf[4];
#pragma unroll
    for (int j = 0; j < 4; ++j)
      af[j] = *(const f16x8*)&lA[(wm + j * 16 + fr) * 32 + fk];
#pragma unroll
    for (int i = 0; i < 4; ++i)
      bf[i] = *(const f16x8*)&lB[(wn + i * 16 + fr) * 32 + fk];
#pragma unroll
    for (int i = 0; i < 4; ++i)
#pragma unroll
      for (int j = 0; j < 4; ++j)
        acc[i][j] = __builtin_amdgcn_mfma_f32_16x16x32_f16(bf[i], af[j], acc[i][j], 0, 0, 0);
    __syncthreads();
  }

  const int c4 = (lane >> 4) << 2;   // col offset
  const int rr = lane & 15;          // row offset
#pragma unroll
  for (int i = 0; i < 4; ++i) {
    const int col = n0 + wn + i * 16 + c4;
    f32x4 bv = bias ? *(const f32x4*)(bias + col) : f32x4{0, 0, 0, 0};
#pragma unroll
    for (int j = 0; j < 4; ++j) {
      const int row = m0 + wm + j * 16 + rr;
      *(f32x4*)(Cf + (size_t)row * ldc + col) = acc[i][j] + bv;
    }
  }
}

// ---------------- fp16 GEMM: C = A * B^T (+res), N-tail-safe ----------------
template <int BN>
__global__ __launch_bounds__(256) void gemm_s(
    const f16* __restrict__ A, const f16* __restrict__ B,
    float* __restrict__ Cf, const float* __restrict__ res,
    int N, int K, int ldc)
{
  constexpr int JN = BN / 32;
  __shared__ f16 lA[4096];
  __shared__ f16 lB[BN * 32];
  const int tid  = threadIdx.x;
  const int lane = tid & 63;
  const int wid  = tid >> 6;
  int bx, by; swz_tiles(bx, by);
  const int m0 = by * 128;
  const int n0 = bx * BN;

  const int r0 = tid >> 2;
  const int kc = (tid & 3) << 3;
  const size_t aoff0 = (size_t)(m0 + r0) * K + kc;
  const size_t aoff1 = aoff0 + (size_t)64 * K;
  int nr0 = n0 + r0;      if (nr0 > N - 1) nr0 = N - 1;
  const size_t boff0 = (size_t)nr0 * K + kc;
  size_t boff1 = 0;
  if constexpr (BN == 128) {
    int nr1 = n0 + 64 + r0; if (nr1 > N - 1) nr1 = N - 1;
    boff1 = (size_t)nr1 * K + kc;
  }

  const int fr = lane & 15;
  const int fk = (lane >> 4) << 3;
  const int wm = (wid >> 1) << 6;
  const int wn = (wid & 1) * (BN / 2);

  f32x4 acc[JN][4] = {};   // [fi col][fj row]

  for (int kk = 0; kk < K; kk += 32) {
    gld16(A + aoff0 + kk, &lA[tid * 8]);
    gld16(A + aoff1 + kk, &lA[2048 + tid * 8]);
    gld16(B + boff0 + kk, &lB[tid * 8]);
    if constexpr (BN == 128)
      gld16(B + boff1 + kk, &lB[2048 + tid * 8]);
    __syncthreads();
    f16x8 af[4], bf[JN];
#pragma unroll
    for (int j = 0; j < 4; ++j)
      af[j] = *(const f16x8*)&lA[(wm + j * 16 + fr) * 32 + fk];
#pragma unroll
    for (int i = 0; i < JN; ++i)
      bf[i] = *(const f16x8*)&lB[(wn + i * 16 + fr) * 32 + fk];
#pragma unroll
    for (int i = 0; i < JN; ++i)
#pragma unroll
      for (int j = 0; j < 4; ++j)
        acc[i][j] = __builtin_amdgcn_mfma_f32_16x16x32_f16(bf[i], af[j], acc[i][j], 0, 0, 0);
    __syncthreads();
  }

  const int c4 = (lane >> 4) << 2;
  const int rr = lane & 15;
#pragma unroll
  for (int i = 0; i < JN; ++i) {
    const int col = n0 + wn + i * 16 + c4;
    if (col >= N) continue;            // col,N multiples of 4 -> x4 safe
#pragma unroll
    for (int j = 0; j < 4; ++j) {
      const int row = m0 + wm + j * 16 + rr;
      size_t off = (size_t)row * ldc + col;
      f32x4 v = acc[i][j];
      if (res) v += *(const f32x4*)(res + off);
      *(f32x4*)(Cf + off) = v;
    }
  }
}

// ---------------- fused UV GEMM: G = f16((A U^T) .* (A V^T)) ----------------
__global__ __launch_bounds__(256) void gemm_uv(
    const f16* __restrict__ A, const f16* __restrict__ B,
    f16* __restrict__ Gh)
{
  __shared__ f16 lA[4096], lB[4096];
  const int tid  = threadIdx.x;
  const int lane = tid & 63;
  const int wid  = tid >> 6;
  int bx, by; swz_tiles(bx, by);
  const int m0 = by * 128;
  const int n0 = bx * 128;
  const int K = DIM;

  const int r0 = tid >> 2;
  const int kc = (tid & 3) << 3;
  const size_t aoff0 = (size_t)(m0 + r0) * K + kc;
  const size_t aoff1 = aoff0 + (size_t)64 * K;

  const int fr = lane & 15;
  const int fk = (lane >> 4) << 3;
  const int wm = (wid >> 1) << 6;
  const int wn = (wid & 1) << 6;

  f32x4 accu[4][4] = {}, accv[4][4] = {};

  auto half_loop = [&](size_t b0, size_t b1, f32x4 (&acc)[4][4]) {
    for (int kk = 0; kk < K; kk += 32) {
      gld16(A + aoff0 + kk, &lA[tid * 8]);
      gld16(A + aoff1 + kk, &lA[2048 + tid * 8]);
      gld16(B + b0 + kk, &lB[tid * 8]);
      gld16(B + b1 + kk, &lB[2048 + tid * 8]);
      __syncthreads();
      f16x8 af[4], bf[4];
#pragma unroll
      for (int j = 0; j < 4; ++j)
        af[j] = *(const f16x8*)&lA[(wm + j * 16 + fr) * 32 + fk];
#pragma unroll
      for (int i = 0; i < 4; ++i)
        bf[i] = *(const f16x8*)&lB[(wn + i * 16 + fr) * 32 + fk];
#pragma unroll
      for (int i = 0; i < 4; ++i)
#pragma unroll
        for (int j = 0; j < 4; ++j)
          acc[i][j] = __builtin_amdgcn_mfma_f32_16x16x32_f16(bf[i], af[j], acc[i][j], 0, 0, 0);
      __syncthreads();
    }
  };

  const size_t bu0 = (size_t)(n0 + r0) * K + kc;
  const size_t bu1 = bu0 + (size_t)64 * K;
  const size_t bv0 = (size_t)(FFN + n0 + r0) * K + kc;
  const size_t bv1 = bv0 + (size_t)64 * K;
  half_loop(bu0, bu1, accu);
  half_loop(bv0, bv1, accv);

  const int c4 = (lane >> 4) << 2;
  const int rr = lane & 15;
#pragma unroll
  for (int i = 0; i < 4; ++i) {
    const int col = n0 + wn + i * 16 + c4;
#pragma unroll
    for (int j = 0; j < 4; ++j) {
      const int row = m0 + wm + j * 16 + rr;
      size_t off = (size_t)row * FFN + col;
      f16x4 h;
#pragma unroll
      for (int r = 0; r < 4; ++r)
        h[r] = (f16)(accu[i][j][r] * accv[i][j][r]);
      *(f16x4*)(Gh + off) = h;
    }
  }
}

// ---------------- small kernels ----------------
__global__ __launch_bounds__(256) void cvt_f2h_k(const float* __restrict__ src,
                                                 f16* __restrict__ dst, int n)
{
  for (size_t i = ((size_t)blockIdx.x * 256 + threadIdx.x) * 4; i < (size_t)n;
       i += (size_t)gridDim.x * 1024) {
    f32x4 v = *(const f32x4*)(src + i);
    f16x4 o;
#pragma unroll
    for (int c = 0; c < 4; ++c) o[c] = (f16)v[c];
    *(f16x4*)(dst + i) = o;
  }
}

__global__ __launch_bounds__(256) void gather_k(const int* __restrict__ tok,
                                                const float* __restrict__ emb,
                                                float* __restrict__ x)
{
  const int row = blockIdx.x;
  const int t = tok[row];
  const f32x4* s = (const f32x4*)(emb + (size_t)t * DIM);
  f32x4* d = (f32x4*)(x + (size_t)row * DIM);
  d[threadIdx.x] = s[threadIdx.x];
}

// rms over 1024; writes f32 and fp16 copies
__global__ __launch_bounds__(256) void rms1024(const float* __restrict__ in,
                                               float* __restrict__ outf,
                                               f16* __restrict__ outh)
{
  const int row = blockIdx.x, tid = threadIdx.x;
  f32x4 v = ((const f32x4*)(in + (size_t)row * DIM))[tid];
  float ss = v[0] * v[0] + v[1] * v[1] + v[2] * v[2] + v[3] * v[3];
  for (int o = 32; o; o >>= 1) ss += __shfl_down(ss, o);
  __shared__ float red[4];
  if ((tid & 63) == 0) red[tid >> 6] = ss;
  __syncthreads();
  ss = red[0] + red[1] + red[2] + red[3];
  const float sc = rsqrtf(ss * (1.f / 1024.f) + 1e-6f);
  f32x4 o4 = v * sc;
  ((f32x4*)(outf + (size_t)row * DIM))[tid] = o4;
  f16x4 h;
#pragma unroll
  for (int c = 0; c < 4; ++c) h[c] = (f16)o4[c];
  ((f16x4*)(outh + (size_t)row * DIM))[tid] = h;
}

// causal depthwise conv (width 4) + bias + silu on xBC slice of zxbcdt
__global__ __launch_bounds__(256) void conv_silu(const float* __restrict__ zx,
                                                 const float* __restrict__ cw,
                                                 const float* __restrict__ cbias,
                                                 float* __restrict__ xbc)
{
  const int t = blockIdx.x;
  const int l = t & (LSEQ - 1);
  for (int c0 = threadIdx.x * 4; c0 < CONVDIM; c0 += 1024) {
    float w[4][4], a[4];
#pragma unroll
    for (int cc = 0; cc < 4; ++cc) {
      f32x4 wv = *(const f32x4*)(cw + (size_t)(c0 + cc) * 4);
      w[cc][0] = wv[0]; w[cc][1] = wv[1]; w[cc][2] = wv[2]; w[cc][3] = wv[3];
      a[cc] = cbias[c0 + cc];
    }
#pragma unroll
    for (int j = 0; j < 4; ++j) {
      int pos = l - 3 + j;
      if (pos < 0) continue;
      f32x4 xv = *(const f32x4*)(zx + (size_t)(t - 3 + j) * DPROJ + DIN + c0);
      a[0] += xv[0] * w[0][j]; a[1] += xv[1] * w[1][j];
      a[2] += xv[2] * w[2][j]; a[3] += xv[3] * w[3][j];
    }
    f32x4 o;
#pragma unroll
    for (int cc = 0; cc < 4; ++cc) o[cc] = a[cc] / (1.f + expf(-a[cc]));
    *(f32x4*)(xbc + (size_t)t * CONVDIM + c0) = o;
  }
}

// dt = softplus(dtraw + bias); a = dt * (-exp(A_log)); ca = cumsum within chunk
__global__ __launch_bounds__(128) void dt_ca(const float* __restrict__ zx,
                                             const float* __restrict__ dtb,
                                             const float* __restrict__ alog,
                                             float* __restrict__ dt,
                                             float* __restrict__ ca)
{
  const int bc = blockIdx.x >> 5, h = blockIdx.x & 31, q = threadIdx.x;
  const int t = bc * 128 + q;
  float raw = zx[(size_t)t * DPROJ + (DIN + CONVDIM) + h] + dtb[h];
  float d = raw > 20.f ? raw : log1pf(expf(raw));
  dt[t * 32 + h] = d;
  float a = -expf(alog[h]) * d;
  __shared__ float s[128];
  s[q] = a;
  __syncthreads();
  for (int off = 1; off < 128; off <<= 1) {
    float v = (q >= off) ? s[q - off] : 0.f;
    __syncthreads();
    s[q] += v;
    __syncthreads();
  }
  ca[(size_t)blockIdx.x * 128 + q] = s[q];
}

// CB[bc][i][j] = sum_n C[i,n]*B[j,n]
__global__ __launch_bounds__(256) void cb_kernel(const float* __restrict__ xbc,
                                                 float* __restrict__ CB)
{
  const int bc = blockIdx.x;
  __shared__ float Bs[128][32], Cs[128][32];
  float acc[8][8] = {};
  const int ti = threadIdx.x >> 4, tj = threadIdx.x & 15;
  for (int n0 = 0; n0 < 128; n0 += 32) {
    __syncthreads();
    for (int e = threadIdx.x; e < 4096; e += 256) {
      int r = e >> 5, c = e & 31;
      const float* row = xbc + (size_t)(bc * 128 + r) * CONVDIM + DIN;
      Bs[r][c] = row[n0 + c];
      Cs[r][c] = row[DSTATE + n0 + c];
    }
    __syncthreads();
    for (int n = 0; n < 32; ++n) {
      float cv[8], bv[8];
#pragma unroll
      for (int ii = 0; ii < 8; ++ii) cv[ii] = Cs[ti * 8 + ii][n];
#pragma unroll
      for (int jj = 0; jj < 8; ++jj) bv[jj] = Bs[tj * 8 + jj][n];
#pragma unroll
      for (int ii = 0; ii < 8; ++ii)
#pragma unroll
        for (int jj = 0; jj < 8; ++jj) acc[ii][jj] += cv[ii] * bv[jj];
    }
  }
  for (int ii = 0; ii < 8; ++ii)
    for (int jj = 0; jj < 8; ++jj)
      CB[(size_t)bc * 16384 + (size_t)(ti * 8 + ii) * 128 + (tj * 8 + jj)] = acc[ii][jj];
}

// y_intra[i][p] = sum_{j<=i} CB[i][j]*exp(ca_i-ca_j)*dt_j*x[j][p]
__global__ __launch_bounds__(256) void yintra(const float* __restrict__ xbc,
                                              const float* __restrict__ dt,
                                              const float* __restrict__ ca,
                                              const float* __restrict__ CB,
                                              float* __restrict__ ybuf)
{
  const int bc = blockIdx.x >> 5, h = blockIdx.x & 31;
  __shared__ float xdt[128][64];
  __shared__ float cas[128];
  const int tid = threadIdx.x;
  if (tid < 128) cas[tid] = ca[(size_t)blockIdx.x * 128 + tid];
  for (int e = tid * 4; e < 8192; e += 1024) {
    int j = e >> 6, p = e & 63;
    f32x4 xv = *(const f32x4*)(xbc + (size_t)(bc * 128 + j) * CONVDIM + h * 64 + p);
    float dj = dt[(size_t)(bc * 128 + j) * 32 + h];
    xv *= dj;
    *(f32x4*)&xdt[j][p] = xv;
  }
  __syncthreads();
  const int i = tid >> 1, pb = (tid & 1) * 32;
  const float cai = cas[i];
  const float* cbrow = CB + (size_t)bc * 16384 + (size_t)i * 128;
  f32x4 acc[8] = {};
  for (int j = 0; j <= i; ++j) {
    float coeff = cbrow[j] * expf(cai - cas[j]);
    const f32x4* xr = (const f32x4*)&xdt[j][pb];
#pragma unroll
    for (int q = 0; q < 8; ++q) acc[q] += coeff * xr[q];
  }
  float* yo = ybuf + (size_t)(bc * 128 + i) * DIN + h * 64 + pb;
#pragma unroll
  for (int q = 0; q < 8; ++q) *(f32x4*)(yo + q * 4) = acc[q];
}

// states[n][p] = sum_j exp(ca_last-ca_j)*dt_j*B[j][n]*x[j][p]   (layout [bc][h][n][p])
__global__ __launch_bounds__(256) void states_k(const float* __restrict__ xbc,
                                                const float* __restrict__ dt,
                                                const float* __restrict__ ca,
                                                float* __restrict__ states)
{
  const int bc = blockIdx.x >> 5, h = blockIdx.x & 31;
  __shared__ float xw[128][64];
  __shared__ float Bs[32][128];
  __shared__ float warr[128];
  const int tid = threadIdx.x;
  if (tid < 128) {
    float cv = ca[(size_t)blockIdx.x * 128 + tid];
    float clast = ca[(size_t)blockIdx.x * 128 + 127];
    warr[tid] = expf(clast - cv) * dt[(size_t)(bc * 128 + tid) * 32 + h];
  }
  __syncthreads();
  for (int e = tid * 4; e < 8192; e += 1024) {
    int j = e >> 6, p = e & 63;
    f32x4 xv = *(const f32x4*)(xbc + (size_t)(bc * 128 + j) * CONVDIM + h * 64 + p);
    *(f32x4*)&xw[j][p] = xv * warr[j];
  }
  const int w = tid >> 6, p = tid & 63;
  f32x4 acc[8] = {};
  for (int jc = 0; jc < 128; jc += 32) {
    __syncthreads();
    for (int e = tid * 4; e < 4096; e += 1024) {
      int j = e >> 7, n = e & 127;
      *(f32x4*)&Bs[j][n] =
          *(const f32x4*)(xbc + (size_t)(bc * 128 + jc + j) * CONVDIM + DIN + n);
    }
    __syncthreads();
    for (int j = 0; j < 32; ++j) {
      float xv = xw[jc + j][p];
      const f32x4* br = (const f32x4*)&Bs[j][w * 32];
#pragma unroll
      for (int q = 0; q < 8; ++q) acc[q] += xv * br[q];
    }
  }
  float* sb = states + (size_t)blockIdx.x * 8192;
#pragma unroll
  for (int q = 0; q < 8; ++q)
#pragma unroll
    for (int c = 0; c < 4; ++c) {
      int n = w * 32 + q * 4 + c;
      sb[(size_t)n * 64 + p] = acc[q][c];
    }
}

// inter-chunk scan: states[bc] := s_prev ; s = s*cd + states
__global__ __launch_bounds__(256) void scan_k(const float* __restrict__ ca,
                                              float* __restrict__ states)
{
  const int b = blockIdx.x >> 10, h = (blockIdx.x >> 5) & 31, seg = blockIdx.x & 31;
  const int e = seg * 256 + threadIdx.x;
  float s = 0.f;
  for (int c = 0; c < CPB; ++c) {
    int bc = b * CPB + c;
    float cd = expf(ca[(size_t)(bc * 32 + h) * 128 + 127]);
    size_t idx = (size_t)(bc * 32 + h) * 8192 + e;
    float v = states[idx];
    states[idx] = s;
    s = s * cd + v;
  }
}

// y += exp(ca_i)*C[i,:]·s_prev[:, p] + D_h * x
__global__ __launch_bounds__(256) void yinter(const float* __restrict__ xbc,
                                              const float* __restrict__ ca,
                                              const float* __restrict__ Dvec,
                                              const float* __restrict__ states,
                                              float* __restrict__ ybuf)
{
  const int bc = blockIdx.x >> 5, h = blockIdx.x & 31;
  __shared__ float sp[128 * 64];
  __shared__ float cas[128];
  const int tid = threadIdx.x;
  if (tid < 128) cas[tid] = ca[(size_t)blockIdx.x * 128 + tid];
  const float* sg = states + (size_t)blockIdx.x * 8192;
  for (int e = tid * 4; e < 8192; e += 1024)
    *(f32x4*)&sp[e] = *(const f32x4*)(sg + e);
  __syncthreads();
  const int i = tid >> 1, pb = (tid & 1) * 32;
  const float* crow = xbc + (size_t)(bc * 128 + i) * CONVDIM + DIN + DSTATE;
  f32x4 acc[8] = {};
  for (int n = 0; n < 128; ++n) {
    float cn = crow[n];
    const f32x4* sr = (const f32x4*)&sp[n * 64 + pb];
#pragma unroll
    for (int q = 0; q < 8; ++q) acc[q] += cn * sr[q];
  }
  const float ei = expf(cas[i]);
  const float dh = Dvec[h];
  const int tg = bc * 128 + i;
  float* yo = ybuf + (size_t)tg * DIN + h * 64 + pb;
  const float* xv = xbc + (size_t)tg * CONVDIM + h * 64 + pb;
#pragma unroll
  for (int q = 0; q < 8; ++q) {
    f32x4 y = *(const f32x4*)(yo + q * 4);
    f32x4 x4 = *(const f32x4*)(xv + q * 4);
    y += ei * acc[q] + dh * x4;
    *(f32x4*)(yo + q * 4) = y;
  }
}

// yg = y*silu(z); rms(2048) * mnorm_w -> fp16 (stride DIN)
__global__ __launch_bounds__(256) void gate_rms(const float* __restrict__ ybuf,
                                                const float* __restrict__ zx,
                                                const float* __restrict__ nw,
                                                f16* __restrict__ outh)
{
  const int row = blockIdx.x, tid = threadIdx.x;
  const float* yr = ybuf + (size_t)row * DIN;
  const float* zr = zx + (size_t)row * DPROJ;
  f32x4 y0 = *(const f32x4*)(yr + tid * 4);
  f32x4 y1 = *(const f32x4*)(yr + 1024 + tid * 4);
  f32x4 z0 = *(const f32x4*)(zr + tid * 4);
  f32x4 z1 = *(const f32x4*)(zr + 1024 + tid * 4);
  f32x4 g0, g1;
#pragma unroll
  for (int c = 0; c < 4; ++c) {
    g0[c] = y0[c] * (z0[c] / (1.f + expf(-z0[c])));
    g1[c] = y1[c] * (z1[c] / (1.f + expf(-z1[c])));
  }
  float ss = 0.f;
#pragma unroll
  for (int c = 0; c < 4; ++c) ss += g0[c] * g0[c] + g1[c] * g1[c];
  for (int o = 32; o; o >>= 1) ss += __shfl_down(ss, o);
  __shared__ float red[4];
  if ((tid & 63) == 0) red[tid >> 6] = ss;
  __syncthreads();
  ss = red[0] + red[1] + red[2] + red[3];
  const float sc = rsqrtf(ss * (1.f / 2048.f) + 1e-6f);
  f32x4 w0 = *(const f32x4*)(nw + tid * 4);
  f32x4 w1 = *(const f32x4*)(nw + 1024 + tid * 4);
  f16x4 h0, h1;
#pragma unroll
  for (int c = 0; c < 4; ++c) {
    h0[c] = (f16)(g0[c] * sc * w0[c]);
    h1[c] = (f16)(g1[c] * sc * w1[c]);
  }
  *(f16x4*)(outh + (size_t)row * DIN + tid * 4) = h0;
  *(f16x4*)(outh + (size_t)row * DIN + 1024 + tid * 4) = h1;
}

// ---------------- launcher ----------------
extern "C" void kernel_launch(void* const* d_in, const int* in_sizes, int n_in,
                              void* d_out, int out_size, void* d_ws, size_t ws_size,
                              hipStream_t stream)
{
  (void)in_sizes; (void)n_in; (void)out_size; (void)ws_size;
  const int*   tokens = (const int*)d_in[0];
  const float* emb    = (const float*)d_in[1];
  const float* lmb    = (const float*)d_in[2];
  const float* inw    = (const float*)d_in[3];
  const float* cw     = (const float*)d_in[4];
  const float* cbias  = (const float*)d_in[5];
  const float* dtb    = (const float*)d_in[6];
  const float* alog   = (const float*)d_in[7];
  const float* Dvec   = (const float*)d_in[8];
  const float* nw     = (const float*)d_in[9];
  const float* outw   = (const float*)d_in[10];
  const float* uw     = (const float*)d_in[11];
  const float* vw     = (const float*)d_in[12];
  const float* ow     = (const float*)d_in[13];

  char* ws = (char*)d_ws;
  size_t off = 0;
  auto alloc = [&](size_t bytes) { void* p = ws + off; off += (bytes + 255) & ~(size_t)255; return p; };
  f16* emb_h  = (f16*)alloc((size_t)VOCAB * DIM * 2);          // 65.5 MB
  f16* w_in   = (f16*)alloc((size_t)DPROJ * DIM * 2);          //  9.0 MB
  f16* w_out  = (f16*)alloc((size_t)DIM * DIN * 2);            //  4.2 MB
  f16* w_uv   = (f16*)alloc((size_t)2 * FFN * DIM * 2);        // 16.8 MB
  f16* w_o    = (f16*)alloc((size_t)DIM * FFN * 2);            //  8.4 MB
  float* xbuf = (float*)alloc((size_t)NTOK * DIM * 4);
  float* xn   = (float*)alloc((size_t)NTOK * DIM * 4);
  f16* xnh    = (f16*)alloc((size_t)NTOK * DIM * 2);
  f16* xh_lm  = (f16*)alloc((size_t)NTOK * DIM * 2);
  float* dtbuf = (float*)alloc((size_t)NTOK * NH * 4);
  float* cabuf = (float*)alloc((size_t)NCHUNK * NH * QLEN * 4);
  float* CBbuf = (float*)alloc((size_t)NCHUNK * QLEN * QLEN * 4);
  f16* abh    = (f16*)alloc((size_t)NTOK * FFN * 2);           // 33.6 MB

  // big transients live in d_out (fully overwritten by the final GEMM)
  char* ob = (char*)d_out;
  float* states = (float*)(ob);                    //  33.6 MB used
  float* zxb    = (float*)(ob + 134217728);        //  71.8 MB
  float* xbc    = (float*)(ob + 206045184);        //  37.7 MB
  float* ybuf   = (float*)(ob + 243793920);        //  33.6 MB

  cvt_f2h_k<<<4096, 256, 0, stream>>>(emb, emb_h, VOCAB * DIM);
  gather_k<<<NTOK, 256, 0, stream>>>(tokens, emb, xbuf);

  for (int it = 0; it < 2 * NLAYER; ++it) {
    const int li = it >> 1;
    if ((it & 1) == 0) {
      cvt_f2h_k<<<2048, 256, 0, stream>>>(inw + (size_t)li * DPROJ * DIM, w_in, DPROJ * DIM);
      cvt_f2h_k<<<1024, 256, 0, stream>>>(outw + (size_t)li * DIM * DIN, w_out, DIM * DIN);
      cvt_f2h_k<<<2048, 256, 0, stream>>>(uw + (size_t)li * FFN * DIM, w_uv, FFN * DIM);
      cvt_f2h_k<<<2048, 256, 0, stream>>>(vw + (size_t)li * FFN * DIM, w_uv + (size_t)FFN * DIM, FFN * DIM);
      cvt_f2h_k<<<2048, 256, 0, stream>>>(ow + (size_t)li * DIM * FFN, w_o, DIM * FFN);
    }
    // x = rms(x) ; mamba
    rms1024<<<NTOK, 256, 0, stream>>>(xbuf, xn, xnh);
    gemm_s<128><<<dim3((DPROJ + 127) / 128, NTOK / 128), 256, 0, stream>>>(
        xnh, w_in, zxb, nullptr, DPROJ, DIM, DPROJ);
    conv_silu<<<NTOK, 256, 0, stream>>>(zxb, cw + (size_t)li * CONVDIM * DCONV,
                                        cbias + (size_t)li * CONVDIM, xbc);
    dt_ca<<<NCHUNK * NH, 128, 0, stream>>>(zxb, dtb + li * NH, alog + li * NH, dtbuf, cabuf);
    cb_kernel<<<NCHUNK, 256, 0, stream>>>(xbc, CBbuf);
    yintra<<<NCHUNK * NH, 256, 0, stream>>>(xbc, dtbuf, cabuf, CBbuf, ybuf);
    states_k<<<NCHUNK * NH, 256, 0, stream>>>(xbc, dtbuf, cabuf, states);
    scan_k<<<2048, 256, 0, stream>>>(cabuf, states);
    yinter<<<NCHUNK * NH, 256, 0, stream>>>(xbc, cabuf, Dvec + li * NH, states, ybuf);
    gate_rms<<<NTOK, 256, 0, stream>>>(ybuf, zxb, nw + (size_t)li * DIN, abh);
    gemm_s<64><<<dim3(DIM / 64, NTOK / 128), 256, 0, stream>>>(
        abh, w_out, xbuf, xn, DIM, DIN, DIM);
    // x = rms(x) ; gated FFN
    rms1024<<<NTOK, 256, 0, stream>>>(xbuf, xn, xnh);
    gemm_uv<<<dim3(FFN / 128, NTOK / 128), 256, 0, stream>>>(
        xnh, w_uv, abh);
    gemm_s<64><<<dim3(DIM / 64, NTOK / 128), 256, 0, stream>>>(
        abh, w_o, xbuf, xn, DIM, FFN, DIM);
  }

  // lm head (single fp16)
  cvt_f2h_k<<<4096, 256, 0, stream>>>(xbuf, xh_lm, NTOK * DIM);
  gemm_bt<<<dim3(VOCAB / 128, NTOK / 128), 256, 0, stream>>>(
      xh_lm, emb_h, (float*)d_out, lmb, VOCAB, DIM, VOCAB);
}